// Round 2
// baseline (3010.954 us; speedup 1.0000x reference)
//
#include <hip/hip_runtime.h>
#include <hip/hip_bf16.h>

#define N_NODES 50000
#define N_EDGES 800000
#define EMB_D 128
#define HID_D 256
#define OUT_D 128
#define NGRAPH 256

// ---------------- degree / norm ----------------
__global__ void deg_kernel(const int* __restrict__ dst, float* __restrict__ deg) {
    int e = blockIdx.x * blockDim.x + threadIdx.x;
    if (e < N_EDGES) atomicAdd(&deg[dst[e]], 1.0f);
}

__global__ void dinv_kernel(float* deg) {
    int i = blockIdx.x * blockDim.x + threadIdx.x;
    if (i < N_NODES) deg[i] = rsqrtf(deg[i] + 1.0f);
}

__global__ void cnt_kernel(const int* __restrict__ batch, int* __restrict__ cnt) {
    int i = blockIdx.x * blockDim.x + threadIdx.x;
    if (i < N_NODES) atomicAdd(&cnt[batch[i]], 1);
}

// ---------------- GEMM: H[N,D] = A[N,K] @ W[K,D] (all fp32) ----------------
// Block: D threads (one col each), R rows per block staged in LDS.
template<int K, int D, int R>
__global__ void gemm_k(const float* __restrict__ A, const float* __restrict__ W,
                       float* __restrict__ H, int n) {
    __shared__ float a[R * K];
    int row0 = blockIdx.x * R;
    for (int t = threadIdx.x; t < R * K; t += D) {
        int r = row0 + t / K;
        a[t] = (r < n) ? A[(size_t)r * K + (t % K)] : 0.f;
    }
    __syncthreads();
    int j = threadIdx.x;
    float acc[R];
#pragma unroll
    for (int r = 0; r < R; ++r) acc[r] = 0.f;
#pragma unroll 4
    for (int k = 0; k < K; ++k) {
        float w = W[k * D + j];
#pragma unroll
        for (int r = 0; r < R; ++r)
            acc[r] += a[r * K + k] * w;
    }
#pragma unroll
    for (int r = 0; r < R; ++r) {
        int row = row0 + r;
        if (row < n) H[(size_t)row * D + j] = acc[r];
    }
}

// First layer: gather embed[node_ids[row]] then GEMM. K=EMB_D, D=HID_D.
template<int R>
__global__ void gemm_gather(const int* __restrict__ ids,
                            const float* __restrict__ embed,
                            const float* __restrict__ W,
                            float* __restrict__ H) {
    __shared__ float a[R * EMB_D];
    int row0 = blockIdx.x * R;
    for (int t = threadIdx.x; t < R * EMB_D; t += HID_D) {
        int row = row0 + t / EMB_D;
        float v = 0.f;
        if (row < N_NODES) {
            int nid = ids[row];
            v = embed[(size_t)nid * EMB_D + (t % EMB_D)];
        }
        a[t] = v;
    }
    __syncthreads();
    int j = threadIdx.x;
    float acc[R];
#pragma unroll
    for (int r = 0; r < R; ++r) acc[r] = 0.f;
#pragma unroll 4
    for (int k = 0; k < EMB_D; ++k) {
        float w = W[k * HID_D + j];
#pragma unroll
        for (int r = 0; r < R; ++r)
            acc[r] += a[r * EMB_D + k] * w;
    }
#pragma unroll
    for (int r = 0; r < R; ++r) {
        int row = row0 + r;
        if (row < N_NODES) H[(size_t)row * HID_D + j] = acc[r];
    }
}

// ---------------- edge aggregation (atomic scatter-add) ----------------
// One wave per edge; lane d handles feature dims d, d+64, ...
template<int D>
__global__ void agg_k(const int* __restrict__ src, const int* __restrict__ dst,
                      const float* __restrict__ dinv, const float* __restrict__ H,
                      float* __restrict__ AGG) {
    int gid = blockIdx.x * blockDim.x + threadIdx.x;
    int e = gid >> 6;
    int lane = gid & 63;
    if (e >= N_EDGES) return;
    int s = src[e], d = dst[e];
    float norm = dinv[s] * dinv[d];
#pragma unroll
    for (int c = lane; c < D; c += 64)
        atomicAdd(&AGG[(size_t)d * D + c], H[(size_t)s * D + c] * norm);
}

// ---------------- post: X = [relu](AGG + H*dinv^2 + b [+ X]) ----------------
template<int D, bool RELU, bool RES>
__global__ void post_k(const float* __restrict__ AGG, const float* __restrict__ H,
                       const float* __restrict__ dinv, const float* __restrict__ b,
                       float* __restrict__ X) {
    int i = blockIdx.x;
    int j = threadIdx.x;
    float di = dinv[i];
    float v = AGG[(size_t)i * D + j] + H[(size_t)i * D + j] * di * di + b[j];
    if (RES) v += X[(size_t)i * D + j];
    if (RELU) v = fmaxf(v, 0.f);
    X[(size_t)i * D + j] = v;
}

// ---------------- graph readout ----------------
__global__ void gsum_kernel(const int* __restrict__ batch, const float* __restrict__ X,
                            float* __restrict__ gsum) {
    int i = blockIdx.x;
    int j = threadIdx.x;  // OUT_D
    atomicAdd(&gsum[batch[i] * OUT_D + j], X[(size_t)i * OUT_D + j]);
}

__global__ void final_kernel(const float* __restrict__ gsum, const int* __restrict__ cnt,
                             float* __restrict__ out) {
    int g = blockIdx.x;
    int j = threadIdx.x;
    int c = cnt[g];
    float cf = (float)(c > 0 ? c : 1);
    out[g * OUT_D + j] = gsum[g * OUT_D + j] / cf;
}

extern "C" void kernel_launch(void* const* d_in, const int* in_sizes, int n_in,
                              void* d_out, int out_size, void* d_ws, size_t ws_size,
                              hipStream_t stream) {
    const int* node_ids = (const int*)d_in[0];
    const int* edge_index = (const int*)d_in[1];
    const int* batch = (const int*)d_in[2];
    const float* embed = (const float*)d_in[3];
    const float* W_in  = (const float*)d_in[4];
    const float* b_in  = (const float*)d_in[5];
    const float* W_h1  = (const float*)d_in[6];
    const float* b_h1  = (const float*)d_in[7];
    const float* W_h2  = (const float*)d_in[8];
    const float* b_h2  = (const float*)d_in[9];
    const float* W_out = (const float*)d_in[10];
    const float* b_out = (const float*)d_in[11];
    float* out = (float*)d_out;

    const int* src = edge_index;
    const int* dst = edge_index + N_EDGES;

    // workspace layout (256B aligned)
    char* w = (char*)d_ws;
    size_t o = 0;
    auto alloc = [&](size_t bytes) -> void* {
        void* p = w + o;
        o = (o + bytes + 255) & ~(size_t)255;
        return p;
    };
    float* dinv = (float*)alloc((size_t)N_NODES * sizeof(float));
    int*   cnt  = (int*)alloc((size_t)NGRAPH * sizeof(int));
    float* gsum = (float*)alloc((size_t)NGRAPH * OUT_D * sizeof(float));
    float* X    = (float*)alloc((size_t)N_NODES * HID_D * sizeof(float));
    float* H    = (float*)alloc((size_t)N_NODES * HID_D * sizeof(float));
    float* AGG  = (float*)alloc((size_t)N_NODES * HID_D * sizeof(float));
    (void)ws_size;

    hipMemsetAsync(dinv, 0, (size_t)N_NODES * sizeof(float), stream);
    hipMemsetAsync(cnt, 0, (size_t)NGRAPH * sizeof(int), stream);
    hipMemsetAsync(gsum, 0, (size_t)NGRAPH * OUT_D * sizeof(float), stream);

    deg_kernel<<<(N_EDGES + 255) / 256, 256, 0, stream>>>(dst, dinv);
    dinv_kernel<<<(N_NODES + 255) / 256, 256, 0, stream>>>(dinv);
    cnt_kernel<<<(N_NODES + 255) / 256, 256, 0, stream>>>(batch, cnt);

    const int R = 8;
    const int gemm_grid = (N_NODES + R - 1) / R;
    const int agg_grid = (N_EDGES * 64) / 256;

    // ---- Layer 1: embed gather + GCNConv(128->256), relu ----
    gemm_gather<R><<<gemm_grid, HID_D, 0, stream>>>(node_ids, embed, W_in, H);
    hipMemsetAsync(AGG, 0, (size_t)N_NODES * HID_D * sizeof(float), stream);
    agg_k<HID_D><<<agg_grid, 256, 0, stream>>>(src, dst, dinv, H, AGG);
    post_k<HID_D, true, false><<<N_NODES, HID_D, 0, stream>>>(AGG, H, dinv, b_in, X);

    // ---- Layer 2: residual GCNConv(256->256), relu ----
    gemm_k<HID_D, HID_D, R><<<gemm_grid, HID_D, 0, stream>>>(X, W_h1, H, N_NODES);
    hipMemsetAsync(AGG, 0, (size_t)N_NODES * HID_D * sizeof(float), stream);
    agg_k<HID_D><<<agg_grid, 256, 0, stream>>>(src, dst, dinv, H, AGG);
    post_k<HID_D, true, true><<<N_NODES, HID_D, 0, stream>>>(AGG, H, dinv, b_h1, X);

    // ---- Layer 3: residual GCNConv(256->256), relu ----
    gemm_k<HID_D, HID_D, R><<<gemm_grid, HID_D, 0, stream>>>(X, W_h2, H, N_NODES);
    hipMemsetAsync(AGG, 0, (size_t)N_NODES * HID_D * sizeof(float), stream);
    agg_k<HID_D><<<agg_grid, 256, 0, stream>>>(src, dst, dinv, H, AGG);
    post_k<HID_D, true, true><<<N_NODES, HID_D, 0, stream>>>(AGG, H, dinv, b_h2, X);

    // ---- Layer 4: GCNConv(256->128), no relu, no residual ----
    gemm_k<HID_D, OUT_D, R><<<gemm_grid, OUT_D, 0, stream>>>(X, W_out, H, N_NODES);
    hipMemsetAsync(AGG, 0, (size_t)N_NODES * OUT_D * sizeof(float), stream);
    agg_k<OUT_D><<<agg_grid, 256, 0, stream>>>(src, dst, dinv, H, AGG);
    post_k<OUT_D, false, false><<<N_NODES, OUT_D, 0, stream>>>(AGG, H, dinv, b_out, X);

    // ---- readout: scatter_mean over batch ----
    gsum_kernel<<<N_NODES, OUT_D, 0, stream>>>(batch, X, gsum);
    final_kernel<<<NGRAPH, OUT_D, 0, stream>>>(gsum, cnt, out);
}

// Round 3
// 1205.207 us; speedup vs baseline: 2.4983x; 2.4983x over previous
//
#include <hip/hip_runtime.h>
#include <hip/hip_bf16.h>

#define N_NODES 50000
#define N_EDGES 800000
#define EMB_D 128
#define HID_D 256
#define OUT_D 128
#define NGRAPH 256

// ---------------- degree / batch-count histograms ----------------
__global__ void deg_kernel(const int* __restrict__ dst, int* __restrict__ deg) {
    int e = blockIdx.x * blockDim.x + threadIdx.x;
    if (e < N_EDGES) atomicAdd(&deg[dst[e]], 1);
}

__global__ void dinv_kernel(const int* __restrict__ deg, float* __restrict__ dinv) {
    int i = blockIdx.x * blockDim.x + threadIdx.x;
    if (i < N_NODES) dinv[i] = rsqrtf((float)deg[i] + 1.0f);
}

__global__ void cnt_kernel(const int* __restrict__ batch, int* __restrict__ cnt) {
    int i = blockIdx.x * blockDim.x + threadIdx.x;
    if (i < N_NODES) atomicAdd(&cnt[batch[i]], 1);
}

// ---------------- exclusive prefix sum over deg -> row_start[N+1] ----------------
// Single block, 1024 threads, blocked scan.
__global__ void scan_kernel(const int* __restrict__ deg, int* __restrict__ row_start,
                            int* __restrict__ cursor) {
    const int T = 1024;
    __shared__ int part[T];
    int tid = threadIdx.x;
    const int chunk = (N_NODES + T - 1) / T;
    int begin = tid * chunk;
    int end = begin + chunk; if (end > N_NODES) end = N_NODES;
    int s = 0;
    for (int i = begin; i < end; ++i) s += deg[i];
    part[tid] = s;
    __syncthreads();
    // Hillis-Steele inclusive scan
    for (int off = 1; off < T; off <<= 1) {
        int v = (tid >= off) ? part[tid - off] : 0;
        __syncthreads();
        part[tid] += v;
        __syncthreads();
    }
    int run = (tid == 0) ? 0 : part[tid - 1];
    for (int i = begin; i < end; ++i) {
        row_start[i] = run;
        cursor[i] = run;
        run += deg[i];
    }
    if (tid == T - 1) row_start[N_NODES] = run;
}

// ---------------- scatter edges into CSR (by dst) ----------------
__global__ void scatter_kernel(const int* __restrict__ src, const int* __restrict__ dst,
                               const float* __restrict__ dinv, int* __restrict__ cursor,
                               int* __restrict__ csr_src, float* __restrict__ csr_norm) {
    int e = blockIdx.x * blockDim.x + threadIdx.x;
    if (e >= N_EDGES) return;
    int s = src[e], d = dst[e];
    int pos = atomicAdd(&cursor[d], 1);
    csr_src[pos] = s;
    csr_norm[pos] = dinv[s] * dinv[d];
}

// ---------------- embedding gather: X0[i,:] = embed[ids[i],:] (float4) ----------------
__global__ void gather_kernel(const int* __restrict__ ids, const float* __restrict__ embed,
                              float* __restrict__ X0) {
    int idx = blockIdx.x * blockDim.x + threadIdx.x;  // one float4 each
    const int V = EMB_D / 4;                           // 32 float4 per row
    if (idx >= N_NODES * V) return;
    int row = idx / V, c = idx % V;
    const float4* e4 = (const float4*)embed;
    float4* x4 = (float4*)X0;
    x4[idx] = e4[(size_t)ids[row] * V + c];
}

// ---------------- fused aggregation: one wave per node ----------------
// out[i] = sum_{e in CSR(i)} norm_e * H[src_e] + dinv[i]^2 * H[i] (+b) (+X res) (relu)
template<int D, bool HASB, bool RES, bool RELU>
__global__ __launch_bounds__(256) void agg_node(
        const int* __restrict__ row_start, const int* __restrict__ csr_src,
        const float* __restrict__ csr_norm, const float* __restrict__ dinv,
        const float* __restrict__ H, const float* __restrict__ b,
        float* __restrict__ X) {
    constexpr int VPL = D / 64;  // floats per lane
    int wave = threadIdx.x >> 6, lane = threadIdx.x & 63;
    int i = blockIdx.x * 4 + wave;
    if (i >= N_NODES) return;
    const int off = lane * VPL;
    float acc0[VPL], acc1[VPL];
#pragma unroll
    for (int v = 0; v < VPL; ++v) { acc0[v] = 0.f; acc1[v] = 0.f; }
    int e0 = row_start[i], e1 = row_start[i + 1];
    int e = e0;
    for (; e + 1 < e1; e += 2) {
        int s0 = csr_src[e], s1 = csr_src[e + 1];
        float n0 = csr_norm[e], n1 = csr_norm[e + 1];
        const float* h0 = H + (size_t)s0 * D + off;
        const float* h1 = H + (size_t)s1 * D + off;
#pragma unroll
        for (int v = 0; v < VPL; ++v) acc0[v] = fmaf(h0[v], n0, acc0[v]);
#pragma unroll
        for (int v = 0; v < VPL; ++v) acc1[v] = fmaf(h1[v], n1, acc1[v]);
    }
    if (e < e1) {
        int s0 = csr_src[e];
        float n0 = csr_norm[e];
        const float* h0 = H + (size_t)s0 * D + off;
#pragma unroll
        for (int v = 0; v < VPL; ++v) acc0[v] = fmaf(h0[v], n0, acc0[v]);
    }
    float di = dinv[i];
    float d2 = di * di;
    const float* hs = H + (size_t)i * D + off;
    float* xp = X + (size_t)i * D + off;
#pragma unroll
    for (int v = 0; v < VPL; ++v) {
        float val = acc0[v] + acc1[v];
        val = fmaf(hs[v], d2, val);
        if (HASB) val += b[off + v];
        if (RES)  val += xp[v];
        if (RELU) val = fmaxf(val, 0.f);
        xp[v] = val;
    }
}

// ---------------- GEMM: H[N,D] = A[N,K] @ W[K,D] (+bias)(+relu) ----------------
template<int K, int D, int R, bool BIAS, bool RELU>
__global__ void gemm_k(const float* __restrict__ A, const float* __restrict__ W,
                       const float* __restrict__ b, float* __restrict__ H, int n) {
    __shared__ float a[R * K];
    int row0 = blockIdx.x * R;
    for (int t = threadIdx.x; t < R * K; t += D) {
        int r = row0 + t / K;
        a[t] = (r < n) ? A[(size_t)r * K + (t % K)] : 0.f;
    }
    __syncthreads();
    int j = threadIdx.x;
    float acc[R];
#pragma unroll
    for (int r = 0; r < R; ++r) acc[r] = 0.f;
#pragma unroll 4
    for (int k = 0; k < K; ++k) {
        float w = W[k * D + j];
#pragma unroll
        for (int r = 0; r < R; ++r)
            acc[r] += a[r * K + k] * w;
    }
    float bj = BIAS ? b[j] : 0.f;
#pragma unroll
    for (int r = 0; r < R; ++r) {
        int row = row0 + r;
        if (row < n) {
            float v = acc[r] + bj;
            if (RELU) v = fmaxf(v, 0.f);
            H[(size_t)row * D + j] = v;
        }
    }
}

// ---------------- graph readout ----------------
__global__ void gsum_kernel(const int* __restrict__ batch, const float* __restrict__ X,
                            float* __restrict__ gsum) {
    int i = blockIdx.x;
    int j = threadIdx.x;  // OUT_D
    atomicAdd(&gsum[batch[i] * OUT_D + j], X[(size_t)i * OUT_D + j]);
}

__global__ void final_kernel(const float* __restrict__ gsum, const int* __restrict__ cnt,
                             float* __restrict__ out) {
    int g = blockIdx.x;
    int j = threadIdx.x;
    int c = cnt[g];
    float cf = (float)(c > 0 ? c : 1);
    out[g * OUT_D + j] = gsum[g * OUT_D + j] / cf;
}

extern "C" void kernel_launch(void* const* d_in, const int* in_sizes, int n_in,
                              void* d_out, int out_size, void* d_ws, size_t ws_size,
                              hipStream_t stream) {
    const int* node_ids = (const int*)d_in[0];
    const int* edge_index = (const int*)d_in[1];
    const int* batch = (const int*)d_in[2];
    const float* embed = (const float*)d_in[3];
    const float* W_in  = (const float*)d_in[4];
    const float* b_in  = (const float*)d_in[5];
    const float* W_h1  = (const float*)d_in[6];
    const float* b_h1  = (const float*)d_in[7];
    const float* W_h2  = (const float*)d_in[8];
    const float* b_h2  = (const float*)d_in[9];
    const float* W_out = (const float*)d_in[10];
    const float* b_out = (const float*)d_in[11];
    float* out = (float*)d_out;

    const int* src = edge_index;
    const int* dst = edge_index + N_EDGES;

    // workspace layout (256B aligned)
    char* w = (char*)d_ws;
    size_t o = 0;
    auto alloc = [&](size_t bytes) -> void* {
        void* p = w + o;
        o = (o + bytes + 255) & ~(size_t)255;
        return p;
    };
    int*   deg      = (int*)alloc((size_t)N_NODES * sizeof(int));
    float* dinv     = (float*)alloc((size_t)N_NODES * sizeof(float));
    int*   cnt      = (int*)alloc((size_t)NGRAPH * sizeof(int));
    float* gsum     = (float*)alloc((size_t)NGRAPH * OUT_D * sizeof(float));
    int*   row_start= (int*)alloc((size_t)(N_NODES + 1) * sizeof(int));
    int*   cursor   = (int*)alloc((size_t)N_NODES * sizeof(int));
    int*   csr_src  = (int*)alloc((size_t)N_EDGES * sizeof(int));
    float* csr_norm = (float*)alloc((size_t)N_EDGES * sizeof(float));
    float* X        = (float*)alloc((size_t)N_NODES * HID_D * sizeof(float));
    float* H        = (float*)alloc((size_t)N_NODES * HID_D * sizeof(float));
    // 128-dim sub-buffers carved out of H
    float* Ha = H;                                  // [N,128]
    float* Hb = H + (size_t)N_NODES * 128;          // [N,128]
    (void)ws_size;

    hipMemsetAsync(deg, 0, (size_t)N_NODES * sizeof(int), stream);
    hipMemsetAsync(cnt, 0, (size_t)NGRAPH * sizeof(int), stream);
    hipMemsetAsync(gsum, 0, (size_t)NGRAPH * OUT_D * sizeof(float), stream);

    deg_kernel<<<(N_EDGES + 255) / 256, 256, 0, stream>>>(dst, deg);
    cnt_kernel<<<(N_NODES + 255) / 256, 256, 0, stream>>>(batch, cnt);
    dinv_kernel<<<(N_NODES + 255) / 256, 256, 0, stream>>>(deg, dinv);
    scan_kernel<<<1, 1024, 0, stream>>>(deg, row_start, cursor);
    scatter_kernel<<<(N_EDGES + 255) / 256, 256, 0, stream>>>(src, dst, dinv, cursor,
                                                              csr_src, csr_norm);

    const int R = 8;
    const int gemm_grid = (N_NODES + R - 1) / R;
    const int agg_grid = (N_NODES + 3) / 4;

    // ---- Layer 1: gather embeddings (128), aggregate at 128, GEMM 128->256 +bias+relu ----
    gather_kernel<<<(N_NODES * (EMB_D / 4) + 255) / 256, 256, 0, stream>>>(node_ids, embed, Ha);
    agg_node<128, false, false, false><<<agg_grid, 256, 0, stream>>>(
        row_start, csr_src, csr_norm, dinv, Ha, nullptr, Hb);
    gemm_k<128, 256, R, true, true><<<gemm_grid, 256, 0, stream>>>(Hb, W_in, b_in, X, N_NODES);

    // ---- Layer 2: GEMM 256->256, fused agg+self+bias+residual+relu ----
    gemm_k<256, 256, R, false, false><<<gemm_grid, 256, 0, stream>>>(X, W_h1, nullptr, H, N_NODES);
    agg_node<256, true, true, true><<<agg_grid, 256, 0, stream>>>(
        row_start, csr_src, csr_norm, dinv, H, b_h1, X);

    // ---- Layer 3: same ----
    gemm_k<256, 256, R, false, false><<<gemm_grid, 256, 0, stream>>>(X, W_h2, nullptr, H, N_NODES);
    agg_node<256, true, true, true><<<agg_grid, 256, 0, stream>>>(
        row_start, csr_src, csr_norm, dinv, H, b_h2, X);

    // ---- Layer 4: GEMM 256->128, aggregate at 128 with bias, no relu ----
    gemm_k<256, 128, R, false, false><<<gemm_grid, 128, 0, stream>>>(X, W_out, nullptr, Ha, N_NODES);
    agg_node<128, true, false, false><<<agg_grid, 256, 0, stream>>>(
        row_start, csr_src, csr_norm, dinv, Ha, b_out, Hb);

    // ---- readout: scatter_mean over batch ----
    gsum_kernel<<<N_NODES, OUT_D, 0, stream>>>(batch, Hb, gsum);
    final_kernel<<<NGRAPH, OUT_D, 0, stream>>>(gsum, cnt, out);
}

// Round 4
// 924.173 us; speedup vs baseline: 3.2580x; 1.3041x over previous
//
#include <hip/hip_runtime.h>
#include <hip/hip_bf16.h>

#define N_NODES 50000
#define N_EDGES 800000
#define EMB_D 128
#define HID_D 256
#define OUT_D 128
#define NGRAPH 256

typedef __attribute__((ext_vector_type(8))) short short8;
typedef __attribute__((ext_vector_type(4))) float floatx4;

__device__ inline void bf16split(float x, short& hi, short& lo) {
    __hip_bfloat16 h = __float2bfloat16(x);
    float r = x - __bfloat162float(h);
    __hip_bfloat16 l = __float2bfloat16(r);
    hi = *reinterpret_cast<short*>(&h);
    lo = *reinterpret_cast<short*>(&l);
}

// ---------------- degree / batch-count histograms ----------------
__global__ void deg_kernel(const int* __restrict__ dst, int* __restrict__ deg) {
    int e = blockIdx.x * blockDim.x + threadIdx.x;
    if (e < N_EDGES) atomicAdd(&deg[dst[e]], 1);
}

__global__ void dinv_kernel(const int* __restrict__ deg, float* __restrict__ dinv) {
    int i = blockIdx.x * blockDim.x + threadIdx.x;
    if (i < N_NODES) dinv[i] = rsqrtf((float)deg[i] + 1.0f);
}

__global__ void cnt_kernel(const int* __restrict__ batch, int* __restrict__ cnt) {
    int i = blockIdx.x * blockDim.x + threadIdx.x;
    if (i < N_NODES) atomicAdd(&cnt[batch[i]], 1);
}

// ---------------- exclusive prefix sum over deg -> row_start[N+1] ----------------
__global__ void scan_kernel(const int* __restrict__ deg, int* __restrict__ row_start,
                            int* __restrict__ cursor) {
    const int T = 1024;
    __shared__ int part[T];
    int tid = threadIdx.x;
    const int chunk = (N_NODES + T - 1) / T;
    int begin = tid * chunk;
    int end = begin + chunk; if (end > N_NODES) end = N_NODES;
    int s = 0;
    for (int i = begin; i < end; ++i) s += deg[i];
    part[tid] = s;
    __syncthreads();
    for (int off = 1; off < T; off <<= 1) {
        int v = (tid >= off) ? part[tid - off] : 0;
        __syncthreads();
        part[tid] += v;
        __syncthreads();
    }
    int run = (tid == 0) ? 0 : part[tid - 1];
    for (int i = begin; i < end; ++i) {
        row_start[i] = run;
        cursor[i] = run;
        run += deg[i];
    }
    if (tid == T - 1) row_start[N_NODES] = run;
}

// ---------------- scatter edges into CSR (by dst) ----------------
__global__ void scatter_kernel(const int* __restrict__ src, const int* __restrict__ dst,
                               const float* __restrict__ dinv, int* __restrict__ cursor,
                               int* __restrict__ csr_src, float* __restrict__ csr_norm) {
    int e = blockIdx.x * blockDim.x + threadIdx.x;
    if (e >= N_EDGES) return;
    int s = src[e], d = dst[e];
    int pos = atomicAdd(&cursor[d], 1);
    csr_src[pos] = s;
    csr_norm[pos] = dinv[s] * dinv[d];
}

// ---------------- embedding gather ----------------
__global__ void gather_kernel(const int* __restrict__ ids, const float* __restrict__ embed,
                              float* __restrict__ X0) {
    int idx = blockIdx.x * blockDim.x + threadIdx.x;
    const int V = EMB_D / 4;
    if (idx >= N_NODES * V) return;
    int row = idx / V, c = idx % V;
    const float4* e4 = (const float4*)embed;
    float4* x4 = (float4*)X0;
    x4[idx] = e4[(size_t)ids[row] * V + c];
}

// ---------------- fused aggregation: one wave per node ----------------
template<int D, bool HASB, bool RES, bool RELU>
__global__ __launch_bounds__(256) void agg_node(
        const int* __restrict__ row_start, const int* __restrict__ csr_src,
        const float* __restrict__ csr_norm, const float* __restrict__ dinv,
        const float* __restrict__ H, const float* __restrict__ b,
        float* __restrict__ X) {
    constexpr int VPL = D / 64;
    int wave = threadIdx.x >> 6, lane = threadIdx.x & 63;
    int i = blockIdx.x * 4 + wave;
    if (i >= N_NODES) return;
    const int off = lane * VPL;
    float acc0[VPL], acc1[VPL];
#pragma unroll
    for (int v = 0; v < VPL; ++v) { acc0[v] = 0.f; acc1[v] = 0.f; }
    int e0 = row_start[i], e1 = row_start[i + 1];
    int e = e0;
    for (; e + 1 < e1; e += 2) {
        int s0 = csr_src[e], s1 = csr_src[e + 1];
        float n0 = csr_norm[e], n1 = csr_norm[e + 1];
        const float* h0 = H + (size_t)s0 * D + off;
        const float* h1 = H + (size_t)s1 * D + off;
#pragma unroll
        for (int v = 0; v < VPL; ++v) acc0[v] = fmaf(h0[v], n0, acc0[v]);
#pragma unroll
        for (int v = 0; v < VPL; ++v) acc1[v] = fmaf(h1[v], n1, acc1[v]);
    }
    if (e < e1) {
        int s0 = csr_src[e];
        float n0 = csr_norm[e];
        const float* h0 = H + (size_t)s0 * D + off;
#pragma unroll
        for (int v = 0; v < VPL; ++v) acc0[v] = fmaf(h0[v], n0, acc0[v]);
    }
    float di = dinv[i];
    float d2 = di * di;
    const float* hs = H + (size_t)i * D + off;
    float* xp = X + (size_t)i * D + off;
#pragma unroll
    for (int v = 0; v < VPL; ++v) {
        float val = acc0[v] + acc1[v];
        val = fmaf(hs[v], d2, val);
        if (HASB) val += b[off + v];
        if (RES)  val += xp[v];
        if (RELU) val = fmaxf(val, 0.f);
        xp[v] = val;
    }
}

// ---------------- W pre-split into B-fragment-major bf16 hi/lo ----------------
// frag idx: (((t*(K/32)+kb)*64 + lane)*8 + j) holds W[kb*32 + (lane>>4)*8 + j][t*16 + (lane&15)]
template<int K, int D>
__global__ void wsplit_k(const float* __restrict__ W, short* __restrict__ hi,
                         short* __restrict__ lo) {
    int idx = blockIdx.x * blockDim.x + threadIdx.x;
    if (idx >= K * D) return;
    int j = idx & 7;
    int l = (idx >> 3) & 63;
    int rest = idx >> 9;
    int kb = rest % (K / 32);
    int t = rest / (K / 32);
    int k = kb * 32 + (l >> 4) * 8 + j;
    int ncol = t * 16 + (l & 15);
    bf16split(W[(size_t)k * D + ncol], hi[idx], lo[idx]);
}

// ---------------- MFMA GEMM: H[N,D] = A[N,K] @ W[K,D] (+bias)(+relu) ----------------
// Split-bf16 3-pass (AhiWhi + AhiWlo + AloWhi). Block = 4 waves, tile 64(M) x D(N).
// Wave w covers cols [w*D/4, (w+1)*D/4), i.e. NT = D/64 n-tiles of 16.
template<int K, int D, bool BIAS, bool RELU>
__global__ __launch_bounds__(256) void gemm_mfma(
        const float* __restrict__ A, const short* __restrict__ Whi,
        const short* __restrict__ Wlo, const float* __restrict__ b,
        float* __restrict__ H, int n) {
    constexpr int LDK = K + 8;           // padded LDS row stride (16B-aligned, 2-way banks)
    constexpr int NT = D / 64;           // n-tiles per wave
    constexpr int KB = K / 32;           // MFMA K-steps
    __shared__ short Ahi[64 * LDK];
    __shared__ short Alo[64 * LDK];

    int row0 = blockIdx.x * 64;
    // ---- stage A tile: fp32 -> bf16 hi/lo in LDS ----
    constexpr int NF4 = 64 * (K / 4);
    for (int idx = threadIdx.x; idx < NF4; idx += 256) {
        int r = idx / (K / 4), c4 = idx % (K / 4);
        float4 v;
        if (row0 + r < n) v = ((const float4*)A)[(size_t)(row0 + r) * (K / 4) + c4];
        else v = make_float4(0.f, 0.f, 0.f, 0.f);
        int base = r * LDK + c4 * 4;
        bf16split(v.x, Ahi[base + 0], Alo[base + 0]);
        bf16split(v.y, Ahi[base + 1], Alo[base + 1]);
        bf16split(v.z, Ahi[base + 2], Alo[base + 2]);
        bf16split(v.w, Ahi[base + 3], Alo[base + 3]);
    }
    __syncthreads();

    int wave = threadIdx.x >> 6, lane = threadIdx.x & 63;
    int quad = lane >> 4, lane15 = lane & 15;

    floatx4 acc[4][NT];
#pragma unroll
    for (int mt = 0; mt < 4; ++mt)
#pragma unroll
        for (int nt = 0; nt < NT; ++nt)
            acc[mt][nt] = (floatx4){0.f, 0.f, 0.f, 0.f};

#pragma unroll
    for (int kb = 0; kb < KB; ++kb) {
        short8 ah[4], al[4];
#pragma unroll
        for (int mt = 0; mt < 4; ++mt) {
            int addr = (mt * 16 + lane15) * LDK + kb * 32 + quad * 8;
            ah[mt] = *(const short8*)&Ahi[addr];
            al[mt] = *(const short8*)&Alo[addr];
        }
        short8 bh[NT], bl[NT];
#pragma unroll
        for (int nt = 0; nt < NT; ++nt) {
            int t = wave * NT + nt;
            size_t fb = ((size_t)(t * KB + kb) * 64 + lane) * 8;
            bh[nt] = *(const short8*)&Whi[fb];
            bl[nt] = *(const short8*)&Wlo[fb];
        }
#pragma unroll
        for (int mt = 0; mt < 4; ++mt)
#pragma unroll
            for (int nt = 0; nt < NT; ++nt) {
                acc[mt][nt] = __builtin_amdgcn_mfma_f32_16x16x32_bf16(ah[mt], bh[nt], acc[mt][nt], 0, 0, 0);
                acc[mt][nt] = __builtin_amdgcn_mfma_f32_16x16x32_bf16(ah[mt], bl[nt], acc[mt][nt], 0, 0, 0);
                acc[mt][nt] = __builtin_amdgcn_mfma_f32_16x16x32_bf16(al[mt], bh[nt], acc[mt][nt], 0, 0, 0);
            }
    }

    // ---- epilogue: C/D map col=lane&15, row=quad*4+reg ----
#pragma unroll
    for (int mt = 0; mt < 4; ++mt) {
#pragma unroll
        for (int nt = 0; nt < NT; ++nt) {
            int col = wave * (NT * 16) + nt * 16 + lane15;
            float bj = BIAS ? b[col] : 0.f;
#pragma unroll
            for (int reg = 0; reg < 4; ++reg) {
                int row = row0 + mt * 16 + quad * 4 + reg;
                if (row < n) {
                    float v = acc[mt][nt][reg] + bj;
                    if (RELU) v = fmaxf(v, 0.f);
                    H[(size_t)row * D + col] = v;
                }
            }
        }
    }
}

// ---------------- graph readout ----------------
__global__ void gsum_kernel(const int* __restrict__ batch, const float* __restrict__ X,
                            float* __restrict__ gsum) {
    int i = blockIdx.x;
    int j = threadIdx.x;
    atomicAdd(&gsum[batch[i] * OUT_D + j], X[(size_t)i * OUT_D + j]);
}

__global__ void final_kernel(const float* __restrict__ gsum, const int* __restrict__ cnt,
                             float* __restrict__ out) {
    int g = blockIdx.x;
    int j = threadIdx.x;
    int c = cnt[g];
    float cf = (float)(c > 0 ? c : 1);
    out[g * OUT_D + j] = gsum[g * OUT_D + j] / cf;
}

extern "C" void kernel_launch(void* const* d_in, const int* in_sizes, int n_in,
                              void* d_out, int out_size, void* d_ws, size_t ws_size,
                              hipStream_t stream) {
    const int* node_ids = (const int*)d_in[0];
    const int* edge_index = (const int*)d_in[1];
    const int* batch = (const int*)d_in[2];
    const float* embed = (const float*)d_in[3];
    const float* W_in  = (const float*)d_in[4];
    const float* b_in  = (const float*)d_in[5];
    const float* W_h1  = (const float*)d_in[6];
    const float* b_h1  = (const float*)d_in[7];
    const float* W_h2  = (const float*)d_in[8];
    const float* b_h2  = (const float*)d_in[9];
    const float* W_out = (const float*)d_in[10];
    const float* b_out = (const float*)d_in[11];
    float* out = (float*)d_out;

    const int* src = edge_index;
    const int* dst = edge_index + N_EDGES;

    char* w = (char*)d_ws;
    size_t o = 0;
    auto alloc = [&](size_t bytes) -> void* {
        void* p = w + o;
        o = (o + bytes + 255) & ~(size_t)255;
        return p;
    };
    int*   deg      = (int*)alloc((size_t)N_NODES * sizeof(int));
    float* dinv     = (float*)alloc((size_t)N_NODES * sizeof(float));
    int*   cnt      = (int*)alloc((size_t)NGRAPH * sizeof(int));
    float* gsum     = (float*)alloc((size_t)NGRAPH * OUT_D * sizeof(float));
    int*   row_start= (int*)alloc((size_t)(N_NODES + 1) * sizeof(int));
    int*   cursor   = (int*)alloc((size_t)N_NODES * sizeof(int));
    int*   csr_src  = (int*)alloc((size_t)N_EDGES * sizeof(int));
    float* csr_norm = (float*)alloc((size_t)N_EDGES * sizeof(float));
    float* X        = (float*)alloc((size_t)N_NODES * HID_D * sizeof(float));
    float* H        = (float*)alloc((size_t)N_NODES * HID_D * sizeof(float));
    short* Whi_in   = (short*)alloc((size_t)EMB_D * HID_D * sizeof(short));
    short* Wlo_in   = (short*)alloc((size_t)EMB_D * HID_D * sizeof(short));
    short* Whi_h1   = (short*)alloc((size_t)HID_D * HID_D * sizeof(short));
    short* Wlo_h1   = (short*)alloc((size_t)HID_D * HID_D * sizeof(short));
    short* Whi_h2   = (short*)alloc((size_t)HID_D * HID_D * sizeof(short));
    short* Wlo_h2   = (short*)alloc((size_t)HID_D * HID_D * sizeof(short));
    short* Whi_out  = (short*)alloc((size_t)HID_D * OUT_D * sizeof(short));
    short* Wlo_out  = (short*)alloc((size_t)HID_D * OUT_D * sizeof(short));
    float* Ha = H;
    float* Hb = H + (size_t)N_NODES * 128;
    (void)ws_size;

    hipMemsetAsync(deg, 0, (size_t)N_NODES * sizeof(int), stream);
    hipMemsetAsync(cnt, 0, (size_t)NGRAPH * sizeof(int), stream);
    hipMemsetAsync(gsum, 0, (size_t)NGRAPH * OUT_D * sizeof(float), stream);

    deg_kernel<<<(N_EDGES + 255) / 256, 256, 0, stream>>>(dst, deg);
    cnt_kernel<<<(N_NODES + 255) / 256, 256, 0, stream>>>(batch, cnt);
    dinv_kernel<<<(N_NODES + 255) / 256, 256, 0, stream>>>(deg, dinv);
    scan_kernel<<<1, 1024, 0, stream>>>(deg, row_start, cursor);
    scatter_kernel<<<(N_EDGES + 255) / 256, 256, 0, stream>>>(src, dst, dinv, cursor,
                                                              csr_src, csr_norm);

    // weight pre-split (small)
    wsplit_k<EMB_D, HID_D><<<(EMB_D * HID_D + 255) / 256, 256, 0, stream>>>(W_in, Whi_in, Wlo_in);
    wsplit_k<HID_D, HID_D><<<(HID_D * HID_D + 255) / 256, 256, 0, stream>>>(W_h1, Whi_h1, Wlo_h1);
    wsplit_k<HID_D, HID_D><<<(HID_D * HID_D + 255) / 256, 256, 0, stream>>>(W_h2, Whi_h2, Wlo_h2);
    wsplit_k<HID_D, OUT_D><<<(HID_D * OUT_D + 255) / 256, 256, 0, stream>>>(W_out, Whi_out, Wlo_out);

    const int gemm_grid = (N_NODES + 63) / 64;
    const int agg_grid = (N_NODES + 3) / 4;

    // ---- Layer 1: gather embeddings (128), aggregate at 128, MFMA GEMM 128->256 +bias+relu ----
    gather_kernel<<<(N_NODES * (EMB_D / 4) + 255) / 256, 256, 0, stream>>>(node_ids, embed, Ha);
    agg_node<128, false, false, false><<<agg_grid, 256, 0, stream>>>(
        row_start, csr_src, csr_norm, dinv, Ha, nullptr, Hb);
    gemm_mfma<128, 256, true, true><<<gemm_grid, 256, 0, stream>>>(Hb, Whi_in, Wlo_in, b_in, X, N_NODES);

    // ---- Layer 2: MFMA GEMM 256->256, fused agg+self+bias+residual+relu ----
    gemm_mfma<256, 256, false, false><<<gemm_grid, 256, 0, stream>>>(X, Whi_h1, Wlo_h1, nullptr, H, N_NODES);
    agg_node<256, true, true, true><<<agg_grid, 256, 0, stream>>>(
        row_start, csr_src, csr_norm, dinv, H, b_h1, X);

    // ---- Layer 3: same ----
    gemm_mfma<256, 256, false, false><<<gemm_grid, 256, 0, stream>>>(X, Whi_h2, Wlo_h2, nullptr, H, N_NODES);
    agg_node<256, true, true, true><<<agg_grid, 256, 0, stream>>>(
        row_start, csr_src, csr_norm, dinv, H, b_h2, X);

    // ---- Layer 4: MFMA GEMM 256->128, aggregate at 128 with bias, no relu ----
    gemm_mfma<256, 128, false, false><<<gemm_grid, 256, 0, stream>>>(X, Whi_out, Wlo_out, nullptr, Ha, N_NODES);
    agg_node<128, true, false, false><<<agg_grid, 256, 0, stream>>>(
        row_start, csr_src, csr_norm, dinv, Ha, b_out, Hb);

    // ---- readout ----
    gsum_kernel<<<N_NODES, OUT_D, 0, stream>>>(batch, Hb, gsum);
    final_kernel<<<NGRAPH, OUT_D, 0, stream>>>(gsum, cnt, out);
}

// Round 5
// 738.191 us; speedup vs baseline: 4.0788x; 1.2519x over previous
//
#include <hip/hip_runtime.h>
#include <hip/hip_bf16.h>

#define N_NODES 50000
#define N_EDGES 800000
#define EMB_D 128
#define HID_D 256
#define OUT_D 128
#define NGRAPH 256

typedef __attribute__((ext_vector_type(8))) short short8;
typedef __attribute__((ext_vector_type(4))) float floatx4;
typedef __attribute__((ext_vector_type(2))) unsigned short ushortx2;
typedef __attribute__((ext_vector_type(4))) unsigned short ushortx4;

__device__ inline void bf16split(float x, short& hi, short& lo) {
    __hip_bfloat16 h = __float2bfloat16(x);
    float r = x - __bfloat162float(h);
    __hip_bfloat16 l = __float2bfloat16(r);
    hi = *reinterpret_cast<short*>(&h);
    lo = *reinterpret_cast<short*>(&l);
}

__device__ inline unsigned short f2b(float f) {
    __hip_bfloat16 h = __float2bfloat16(f);
    return *reinterpret_cast<unsigned short*>(&h);
}

__device__ inline float b2f(unsigned short u) {
    union { unsigned int i; float f; } c;
    c.i = ((unsigned int)u) << 16;
    return c.f;
}

template<int VPL> struct UVec;
template<> struct UVec<2> { using T = ushortx2; };
template<> struct UVec<4> { using T = ushortx4; };

// ---------------- degree / batch-count histograms ----------------
__global__ void deg_kernel(const int* __restrict__ dst, int* __restrict__ deg) {
    int e = blockIdx.x * blockDim.x + threadIdx.x;
    if (e < N_EDGES) atomicAdd(&deg[dst[e]], 1);
}

__global__ void dinv_kernel(const int* __restrict__ deg, float* __restrict__ dinv) {
    int i = blockIdx.x * blockDim.x + threadIdx.x;
    if (i < N_NODES) dinv[i] = rsqrtf((float)deg[i] + 1.0f);
}

__global__ void cnt_kernel(const int* __restrict__ batch, int* __restrict__ cnt) {
    int i = blockIdx.x * blockDim.x + threadIdx.x;
    if (i < N_NODES) atomicAdd(&cnt[batch[i]], 1);
}

// ---------------- exclusive prefix sum over deg -> row_start[N+1] ----------------
__global__ void scan_kernel(const int* __restrict__ deg, int* __restrict__ row_start,
                            int* __restrict__ cursor) {
    const int T = 1024;
    __shared__ int part[T];
    int tid = threadIdx.x;
    const int chunk = (N_NODES + T - 1) / T;
    int begin = tid * chunk;
    int end = begin + chunk; if (end > N_NODES) end = N_NODES;
    int s = 0;
    for (int i = begin; i < end; ++i) s += deg[i];
    part[tid] = s;
    __syncthreads();
    for (int off = 1; off < T; off <<= 1) {
        int v = (tid >= off) ? part[tid - off] : 0;
        __syncthreads();
        part[tid] += v;
        __syncthreads();
    }
    int run = (tid == 0) ? 0 : part[tid - 1];
    for (int i = begin; i < end; ++i) {
        row_start[i] = run;
        cursor[i] = run;
        run += deg[i];
    }
    if (tid == T - 1) row_start[N_NODES] = run;
}

// ---------------- scatter edges into CSR (by dst) ----------------
__global__ void scatter_kernel(const int* __restrict__ src, const int* __restrict__ dst,
                               const float* __restrict__ dinv, int* __restrict__ cursor,
                               int* __restrict__ csr_src, float* __restrict__ csr_norm) {
    int e = blockIdx.x * blockDim.x + threadIdx.x;
    if (e >= N_EDGES) return;
    int s = src[e], d = dst[e];
    int pos = atomicAdd(&cursor[d], 1);
    csr_src[pos] = s;
    csr_norm[pos] = dinv[s] * dinv[d];
}

// ---------------- embedding gather -> bf16 rows ----------------
__global__ void gather_bf16(const int* __restrict__ ids, const float* __restrict__ embed,
                            unsigned short* __restrict__ X0) {
    int idx = blockIdx.x * blockDim.x + threadIdx.x;  // one float4 each
    const int V = EMB_D / 4;
    if (idx >= N_NODES * V) return;
    int row = idx / V, c = idx % V;
    float4 v = ((const float4*)embed)[(size_t)ids[row] * V + c];
    ushortx4 u;
    u[0] = f2b(v.x); u[1] = f2b(v.y); u[2] = f2b(v.z); u[3] = f2b(v.w);
    ((ushortx4*)X0)[idx] = u;
}

// ---------------- fused aggregation (bf16 gather, fp32 out): one wave per node ----
// OUT[i] = sum_e norm_e*H[src_e] + dinv[i]^2*H[i] (+b) (+Xres) (relu)
template<int D, bool HASB, bool RES, bool RELU>
__global__ __launch_bounds__(256) void agg_node(
        const int* __restrict__ row_start, const int* __restrict__ csr_src,
        const float* __restrict__ csr_norm, const float* __restrict__ dinv,
        const unsigned short* __restrict__ H, const float* __restrict__ b,
        float* __restrict__ OUT) {
    constexpr int VPL = D / 64;
    using UV = typename UVec<VPL>::T;
    int wave = threadIdx.x >> 6, lane = threadIdx.x & 63;
    int i = blockIdx.x * 4 + wave;
    if (i >= N_NODES) return;
    const int off = lane * VPL;
    float acc0[VPL], acc1[VPL];
#pragma unroll
    for (int v = 0; v < VPL; ++v) { acc0[v] = 0.f; acc1[v] = 0.f; }
    int e0 = row_start[i], e1 = row_start[i + 1];
    int e = e0;
    for (; e + 3 < e1; e += 4) {
        int s0 = csr_src[e], s1 = csr_src[e + 1], s2 = csr_src[e + 2], s3 = csr_src[e + 3];
        float n0 = csr_norm[e], n1 = csr_norm[e + 1], n2 = csr_norm[e + 2], n3 = csr_norm[e + 3];
        UV u0 = *(const UV*)(H + (size_t)s0 * D + off);
        UV u1 = *(const UV*)(H + (size_t)s1 * D + off);
        UV u2 = *(const UV*)(H + (size_t)s2 * D + off);
        UV u3 = *(const UV*)(H + (size_t)s3 * D + off);
#pragma unroll
        for (int v = 0; v < VPL; ++v) acc0[v] = fmaf(b2f(u0[v]), n0, acc0[v]);
#pragma unroll
        for (int v = 0; v < VPL; ++v) acc1[v] = fmaf(b2f(u1[v]), n1, acc1[v]);
#pragma unroll
        for (int v = 0; v < VPL; ++v) acc0[v] = fmaf(b2f(u2[v]), n2, acc0[v]);
#pragma unroll
        for (int v = 0; v < VPL; ++v) acc1[v] = fmaf(b2f(u3[v]), n3, acc1[v]);
    }
    for (; e < e1; ++e) {
        int s0 = csr_src[e];
        float n0 = csr_norm[e];
        UV u0 = *(const UV*)(H + (size_t)s0 * D + off);
#pragma unroll
        for (int v = 0; v < VPL; ++v) acc0[v] = fmaf(b2f(u0[v]), n0, acc0[v]);
    }
    float di = dinv[i];
    float d2 = di * di;
    UV us = *(const UV*)(H + (size_t)i * D + off);
    float* xp = OUT + (size_t)i * D + off;
#pragma unroll
    for (int v = 0; v < VPL; ++v) {
        float val = acc0[v] + acc1[v];
        val = fmaf(b2f(us[v]), d2, val);
        if (HASB) val += b[off + v];
        if (RES)  val += xp[v];
        if (RELU) val = fmaxf(val, 0.f);
        xp[v] = val;
    }
}

// ---------------- W pre-split into B-fragment-major bf16 hi/lo ----------------
template<int K, int D>
__global__ void wsplit_k(const float* __restrict__ W, short* __restrict__ hi,
                         short* __restrict__ lo) {
    int idx = blockIdx.x * blockDim.x + threadIdx.x;
    if (idx >= K * D) return;
    int j = idx & 7;
    int l = (idx >> 3) & 63;
    int rest = idx >> 9;
    int kb = rest % (K / 32);
    int t = rest / (K / 32);
    int k = kb * 32 + (l >> 4) * 8 + j;
    int ncol = t * 16 + (l & 15);
    bf16split(W[(size_t)k * D + ncol], hi[idx], lo[idx]);
}

// ---------------- MFMA GEMM: Hout[N,D] = A[N,K] @ W[K,D] (+bias)(+relu) ----------------
// Split-bf16 3-pass. Block = 4 waves, tile 64(M) x D(N). OUTBF: store bf16 else fp32.
template<int K, int D, bool BIAS, bool RELU, bool OUTBF>
__global__ __launch_bounds__(256) void gemm_mfma(
        const float* __restrict__ A, const short* __restrict__ Whi,
        const short* __restrict__ Wlo, const float* __restrict__ b,
        void* __restrict__ Hout, int n) {
    constexpr int LDK = K + 8;
    constexpr int NT = D / 64;
    constexpr int KB = K / 32;
    __shared__ short Ahi[64 * LDK];
    __shared__ short Alo[64 * LDK];

    int row0 = blockIdx.x * 64;
    constexpr int NF4 = 64 * (K / 4);
    for (int idx = threadIdx.x; idx < NF4; idx += 256) {
        int r = idx / (K / 4), c4 = idx % (K / 4);
        float4 v;
        if (row0 + r < n) v = ((const float4*)A)[(size_t)(row0 + r) * (K / 4) + c4];
        else v = make_float4(0.f, 0.f, 0.f, 0.f);
        int base = r * LDK + c4 * 4;
        bf16split(v.x, Ahi[base + 0], Alo[base + 0]);
        bf16split(v.y, Ahi[base + 1], Alo[base + 1]);
        bf16split(v.z, Ahi[base + 2], Alo[base + 2]);
        bf16split(v.w, Ahi[base + 3], Alo[base + 3]);
    }
    __syncthreads();

    int wave = threadIdx.x >> 6, lane = threadIdx.x & 63;
    int quad = lane >> 4, lane15 = lane & 15;

    floatx4 acc[4][NT];
#pragma unroll
    for (int mt = 0; mt < 4; ++mt)
#pragma unroll
        for (int nt = 0; nt < NT; ++nt)
            acc[mt][nt] = (floatx4){0.f, 0.f, 0.f, 0.f};

#pragma unroll
    for (int kb = 0; kb < KB; ++kb) {
        short8 ah[4], al[4];
#pragma unroll
        for (int mt = 0; mt < 4; ++mt) {
            int addr = (mt * 16 + lane15) * LDK + kb * 32 + quad * 8;
            ah[mt] = *(const short8*)&Ahi[addr];
            al[mt] = *(const short8*)&Alo[addr];
        }
        short8 bh[NT], bl[NT];
#pragma unroll
        for (int nt = 0; nt < NT; ++nt) {
            int t = wave * NT + nt;
            size_t fb = ((size_t)(t * KB + kb) * 64 + lane) * 8;
            bh[nt] = *(const short8*)&Whi[fb];
            bl[nt] = *(const short8*)&Wlo[fb];
        }
#pragma unroll
        for (int mt = 0; mt < 4; ++mt)
#pragma unroll
            for (int nt = 0; nt < NT; ++nt) {
                acc[mt][nt] = __builtin_amdgcn_mfma_f32_16x16x32_bf16(ah[mt], bh[nt], acc[mt][nt], 0, 0, 0);
                acc[mt][nt] = __builtin_amdgcn_mfma_f32_16x16x32_bf16(ah[mt], bl[nt], acc[mt][nt], 0, 0, 0);
                acc[mt][nt] = __builtin_amdgcn_mfma_f32_16x16x32_bf16(al[mt], bh[nt], acc[mt][nt], 0, 0, 0);
            }
    }

#pragma unroll
    for (int mt = 0; mt < 4; ++mt) {
#pragma unroll
        for (int nt = 0; nt < NT; ++nt) {
            int col = wave * (NT * 16) + nt * 16 + lane15;
            float bj = BIAS ? b[col] : 0.f;
#pragma unroll
            for (int reg = 0; reg < 4; ++reg) {
                int row = row0 + mt * 16 + quad * 4 + reg;
                if (row < n) {
                    float v = acc[mt][nt][reg] + bj;
                    if (RELU) v = fmaxf(v, 0.f);
                    if (OUTBF) ((unsigned short*)Hout)[(size_t)row * D + col] = f2b(v);
                    else       ((float*)Hout)[(size_t)row * D + col] = v;
                }
            }
        }
    }
}

// ---------------- graph readout ----------------
__global__ void gsum_kernel(const int* __restrict__ batch, const float* __restrict__ X,
                            float* __restrict__ gsum) {
    int i = blockIdx.x;
    int j = threadIdx.x;
    atomicAdd(&gsum[batch[i] * OUT_D + j], X[(size_t)i * OUT_D + j]);
}

__global__ void final_kernel(const float* __restrict__ gsum, const int* __restrict__ cnt,
                             float* __restrict__ out) {
    int g = blockIdx.x;
    int j = threadIdx.x;
    int c = cnt[g];
    float cf = (float)(c > 0 ? c : 1);
    out[g * OUT_D + j] = gsum[g * OUT_D + j] / cf;
}

extern "C" void kernel_launch(void* const* d_in, const int* in_sizes, int n_in,
                              void* d_out, int out_size, void* d_ws, size_t ws_size,
                              hipStream_t stream) {
    const int* node_ids = (const int*)d_in[0];
    const int* edge_index = (const int*)d_in[1];
    const int* batch = (const int*)d_in[2];
    const float* embed = (const float*)d_in[3];
    const float* W_in  = (const float*)d_in[4];
    const float* b_in  = (const float*)d_in[5];
    const float* W_h1  = (const float*)d_in[6];
    const float* b_h1  = (const float*)d_in[7];
    const float* W_h2  = (const float*)d_in[8];
    const float* b_h2  = (const float*)d_in[9];
    const float* W_out = (const float*)d_in[10];
    const float* b_out = (const float*)d_in[11];
    float* out = (float*)d_out;

    const int* src = edge_index;
    const int* dst = edge_index + N_EDGES;

    char* w = (char*)d_ws;
    size_t o = 0;
    auto alloc = [&](size_t bytes) -> void* {
        void* p = w + o;
        o = (o + bytes + 255) & ~(size_t)255;
        return p;
    };
    int*   deg      = (int*)alloc((size_t)N_NODES * sizeof(int));
    float* dinv     = (float*)alloc((size_t)N_NODES * sizeof(float));
    int*   cnt      = (int*)alloc((size_t)NGRAPH * sizeof(int));
    float* gsum     = (float*)alloc((size_t)NGRAPH * OUT_D * sizeof(float));
    int*   row_start= (int*)alloc((size_t)(N_NODES + 1) * sizeof(int));
    int*   cursor   = (int*)alloc((size_t)N_NODES * sizeof(int));
    int*   csr_src  = (int*)alloc((size_t)N_EDGES * sizeof(int));
    float* csr_norm = (float*)alloc((size_t)N_EDGES * sizeof(float));
    float* X        = (float*)alloc((size_t)N_NODES * HID_D * sizeof(float));     // fp32 residual
    unsigned short* H16 = (unsigned short*)alloc((size_t)N_NODES * HID_D * sizeof(short)); // bf16 GEMM out
    float* A1       = (float*)alloc((size_t)N_NODES * 128 * sizeof(float));       // fp32 agg out (128-d)
    short* Whi_in   = (short*)alloc((size_t)EMB_D * HID_D * sizeof(short));
    short* Wlo_in   = (short*)alloc((size_t)EMB_D * HID_D * sizeof(short));
    short* Whi_h1   = (short*)alloc((size_t)HID_D * HID_D * sizeof(short));
    short* Wlo_h1   = (short*)alloc((size_t)HID_D * HID_D * sizeof(short));
    short* Whi_h2   = (short*)alloc((size_t)HID_D * HID_D * sizeof(short));
    short* Wlo_h2   = (short*)alloc((size_t)HID_D * HID_D * sizeof(short));
    short* Whi_out  = (short*)alloc((size_t)HID_D * OUT_D * sizeof(short));
    short* Wlo_out  = (short*)alloc((size_t)HID_D * OUT_D * sizeof(short));
    unsigned short* E16 = H16;               // layer-1 bf16 embeddings alias (H16 unused then)
    unsigned short* H4  = H16;               // layer-4 bf16 GEMM out [N,128] alias
    (void)ws_size;

    hipMemsetAsync(deg, 0, (size_t)N_NODES * sizeof(int), stream);
    hipMemsetAsync(cnt, 0, (size_t)NGRAPH * sizeof(int), stream);
    hipMemsetAsync(gsum, 0, (size_t)NGRAPH * OUT_D * sizeof(float), stream);

    deg_kernel<<<(N_EDGES + 255) / 256, 256, 0, stream>>>(dst, deg);
    cnt_kernel<<<(N_NODES + 255) / 256, 256, 0, stream>>>(batch, cnt);
    dinv_kernel<<<(N_NODES + 255) / 256, 256, 0, stream>>>(deg, dinv);
    scan_kernel<<<1, 1024, 0, stream>>>(deg, row_start, cursor);
    scatter_kernel<<<(N_EDGES + 255) / 256, 256, 0, stream>>>(src, dst, dinv, cursor,
                                                              csr_src, csr_norm);

    wsplit_k<EMB_D, HID_D><<<(EMB_D * HID_D + 255) / 256, 256, 0, stream>>>(W_in, Whi_in, Wlo_in);
    wsplit_k<HID_D, HID_D><<<(HID_D * HID_D + 255) / 256, 256, 0, stream>>>(W_h1, Whi_h1, Wlo_h1);
    wsplit_k<HID_D, HID_D><<<(HID_D * HID_D + 255) / 256, 256, 0, stream>>>(W_h2, Whi_h2, Wlo_h2);
    wsplit_k<HID_D, OUT_D><<<(HID_D * OUT_D + 255) / 256, 256, 0, stream>>>(W_out, Whi_out, Wlo_out);

    const int gemm_grid = (N_NODES + 63) / 64;
    const int agg_grid = (N_NODES + 3) / 4;

    // ---- Layer 1: gather emb (bf16, 128), agg at 128, MFMA GEMM 128->256 +bias+relu ----
    gather_bf16<<<(N_NODES * (EMB_D / 4) + 255) / 256, 256, 0, stream>>>(node_ids, embed, E16);
    agg_node<128, false, false, false><<<agg_grid, 256, 0, stream>>>(
        row_start, csr_src, csr_norm, dinv, E16, nullptr, A1);
    gemm_mfma<128, 256, true, true, false><<<gemm_grid, 256, 0, stream>>>(A1, Whi_in, Wlo_in, b_in, X, N_NODES);

    // ---- Layer 2: MFMA GEMM 256->256 (bf16 out), fused agg+self+bias+residual+relu ----
    gemm_mfma<256, 256, false, false, true><<<gemm_grid, 256, 0, stream>>>(X, Whi_h1, Wlo_h1, nullptr, H16, N_NODES);
    agg_node<256, true, true, true><<<agg_grid, 256, 0, stream>>>(
        row_start, csr_src, csr_norm, dinv, H16, b_h1, X);

    // ---- Layer 3: same ----
    gemm_mfma<256, 256, false, false, true><<<gemm_grid, 256, 0, stream>>>(X, Whi_h2, Wlo_h2, nullptr, H16, N_NODES);
    agg_node<256, true, true, true><<<agg_grid, 256, 0, stream>>>(
        row_start, csr_src, csr_norm, dinv, H16, b_h2, X);

    // ---- Layer 4: MFMA GEMM 256->128 (bf16 out), agg at 128 +bias ----
    gemm_mfma<256, 128, false, false, true><<<gemm_grid, 256, 0, stream>>>(X, Whi_out, Wlo_out, nullptr, H4, N_NODES);
    agg_node<128, true, false, false><<<agg_grid, 256, 0, stream>>>(
        row_start, csr_src, csr_norm, dinv, H4, b_out, A1);

    // ---- readout ----
    gsum_kernel<<<N_NODES, OUT_D, 0, stream>>>(batch, A1, gsum);
    final_kernel<<<NGRAPH, OUT_D, 0, stream>>>(gsum, cnt, out);
}

// Round 6
// 625.173 us; speedup vs baseline: 4.8162x; 1.1808x over previous
//
#include <hip/hip_runtime.h>
#include <hip/hip_bf16.h>

#define N_NODES 50000
#define N_EDGES 800000
#define EMB_D 128
#define HID_D 256
#define OUT_D 128
#define NGRAPH 256

#define SCAN_B ((N_NODES + 256) / 256)   // 196 blocks covers N_NODES+1 slots

typedef __attribute__((ext_vector_type(8))) short short8;
typedef __attribute__((ext_vector_type(4))) float floatx4;
typedef __attribute__((ext_vector_type(2))) unsigned short ushortx2;
typedef __attribute__((ext_vector_type(4))) unsigned short ushortx4;

__device__ inline void bf16split(float x, short& hi, short& lo) {
    __hip_bfloat16 h = __float2bfloat16(x);
    float r = x - __bfloat162float(h);
    __hip_bfloat16 l = __float2bfloat16(r);
    hi = *reinterpret_cast<short*>(&h);
    lo = *reinterpret_cast<short*>(&l);
}

__device__ inline unsigned short f2b(float f) {
    __hip_bfloat16 h = __float2bfloat16(f);
    return *reinterpret_cast<unsigned short*>(&h);
}

__device__ inline float b2f(unsigned short u) {
    union { unsigned int i; float f; } c;
    c.i = ((unsigned int)u) << 16;
    return c.f;
}

template<int VPL> struct UVec;
template<> struct UVec<2> { using T = ushortx2; };
template<> struct UVec<4> { using T = ushortx4; };

// ---------------- fused degree + batch-count histograms ----------------
__global__ void deg_cnt_kernel(const int* __restrict__ dst, const int* __restrict__ batch,
                               int* __restrict__ deg, int* __restrict__ cnt) {
    int e = blockIdx.x * blockDim.x + threadIdx.x;
    if (e < N_EDGES) atomicAdd(&deg[dst[e]], 1);
    if (e < N_NODES) atomicAdd(&cnt[batch[e]], 1);
}

// ---------------- multi-block scan, phase A: block sums (+ dinv) ----------------
__global__ void scan_a(const int* __restrict__ deg, int* __restrict__ bsum,
                       float* __restrict__ dinv) {
    __shared__ int red[256];
    int t = threadIdx.x;
    int i = blockIdx.x * 256 + t;
    int v = (i < N_NODES) ? deg[i] : 0;
    if (i < N_NODES) dinv[i] = rsqrtf((float)v + 1.0f);
    red[t] = v;
    __syncthreads();
    for (int off = 128; off > 0; off >>= 1) {
        if (t < off) red[t] += red[t + off];
        __syncthreads();
    }
    if (t == 0) bsum[blockIdx.x] = red[0];
}

// ---------------- phase B: exclusive scan of block sums (1 block) ----------------
__global__ void scan_b(const int* __restrict__ bsum, int* __restrict__ boff) {
    __shared__ int s[256];
    int t = threadIdx.x;
    s[t] = (t < SCAN_B) ? bsum[t] : 0;
    __syncthreads();
    for (int off = 1; off < 256; off <<= 1) {
        int v = (t >= off) ? s[t - off] : 0;
        __syncthreads();
        s[t] += v;
        __syncthreads();
    }
    if (t < SCAN_B) boff[t] = (t == 0) ? 0 : s[t - 1];
}

// ---------------- phase C: in-block scan + offset -> row_start, cursor ----------------
__global__ void scan_c(const int* __restrict__ deg, const int* __restrict__ boff,
                       int* __restrict__ row_start, int* __restrict__ cursor) {
    __shared__ int s[256];
    int t = threadIdx.x;
    int i = blockIdx.x * 256 + t;
    int v = (i < N_NODES) ? deg[i] : 0;
    s[t] = v;
    __syncthreads();
    for (int off = 1; off < 256; off <<= 1) {
        int x = (t >= off) ? s[t - off] : 0;
        __syncthreads();
        s[t] += x;
        __syncthreads();
    }
    int excl = s[t] - v;  // exclusive in-block prefix
    int rs = boff[blockIdx.x] + excl;
    if (i < N_NODES) {
        row_start[i] = rs;
        cursor[i] = rs;
    } else if (i == N_NODES) {
        row_start[N_NODES] = rs;
    }
}

// ---------------- scatter edges into CSR (by dst) ----------------
__global__ void scatter_kernel(const int* __restrict__ src, const int* __restrict__ dst,
                               const float* __restrict__ dinv, int* __restrict__ cursor,
                               int* __restrict__ csr_src, float* __restrict__ csr_norm) {
    int e = blockIdx.x * blockDim.x + threadIdx.x;
    if (e >= N_EDGES) return;
    int s = src[e], d = dst[e];
    int pos = atomicAdd(&cursor[d], 1);
    csr_src[pos] = s;
    csr_norm[pos] = dinv[s] * dinv[d];
}

// ---------------- embedding gather -> bf16 rows ----------------
__global__ void gather_bf16(const int* __restrict__ ids, const float* __restrict__ embed,
                            unsigned short* __restrict__ X0) {
    int idx = blockIdx.x * blockDim.x + threadIdx.x;  // one float4 each
    const int V = EMB_D / 4;
    if (idx >= N_NODES * V) return;
    int row = idx / V, c = idx % V;
    float4 v = ((const float4*)embed)[(size_t)ids[row] * V + c];
    ushortx4 u;
    u[0] = f2b(v.x); u[1] = f2b(v.y); u[2] = f2b(v.z); u[3] = f2b(v.w);
    ((ushortx4*)X0)[idx] = u;
}

// ---------------- fused aggregation (bf16 gather, fp32 out): one wave per node ----
template<int D, bool HASB, bool RES, bool RELU>
__global__ __launch_bounds__(256) void agg_node(
        const int* __restrict__ row_start, const int* __restrict__ csr_src,
        const float* __restrict__ csr_norm, const float* __restrict__ dinv,
        const unsigned short* __restrict__ H, const float* __restrict__ b,
        float* __restrict__ OUT) {
    constexpr int VPL = D / 64;
    using UV = typename UVec<VPL>::T;
    int wave = threadIdx.x >> 6, lane = threadIdx.x & 63;
    int i = blockIdx.x * 4 + wave;
    if (i >= N_NODES) return;
    const int off = lane * VPL;
    float acc0[VPL], acc1[VPL];
#pragma unroll
    for (int v = 0; v < VPL; ++v) { acc0[v] = 0.f; acc1[v] = 0.f; }
    int e0 = row_start[i], e1 = row_start[i + 1];
    int e = e0;
    for (; e + 3 < e1; e += 4) {
        int s0 = csr_src[e], s1 = csr_src[e + 1], s2 = csr_src[e + 2], s3 = csr_src[e + 3];
        float n0 = csr_norm[e], n1 = csr_norm[e + 1], n2 = csr_norm[e + 2], n3 = csr_norm[e + 3];
        UV u0 = *(const UV*)(H + (size_t)s0 * D + off);
        UV u1 = *(const UV*)(H + (size_t)s1 * D + off);
        UV u2 = *(const UV*)(H + (size_t)s2 * D + off);
        UV u3 = *(const UV*)(H + (size_t)s3 * D + off);
#pragma unroll
        for (int v = 0; v < VPL; ++v) acc0[v] = fmaf(b2f(u0[v]), n0, acc0[v]);
#pragma unroll
        for (int v = 0; v < VPL; ++v) acc1[v] = fmaf(b2f(u1[v]), n1, acc1[v]);
#pragma unroll
        for (int v = 0; v < VPL; ++v) acc0[v] = fmaf(b2f(u2[v]), n2, acc0[v]);
#pragma unroll
        for (int v = 0; v < VPL; ++v) acc1[v] = fmaf(b2f(u3[v]), n3, acc1[v]);
    }
    for (; e < e1; ++e) {
        int s0 = csr_src[e];
        float n0 = csr_norm[e];
        UV u0 = *(const UV*)(H + (size_t)s0 * D + off);
#pragma unroll
        for (int v = 0; v < VPL; ++v) acc0[v] = fmaf(b2f(u0[v]), n0, acc0[v]);
    }
    float di = dinv[i];
    float d2 = di * di;
    UV us = *(const UV*)(H + (size_t)i * D + off);
    float* xp = OUT + (size_t)i * D + off;
#pragma unroll
    for (int v = 0; v < VPL; ++v) {
        float val = acc0[v] + acc1[v];
        val = fmaf(b2f(us[v]), d2, val);
        if (HASB) val += b[off + v];
        if (RES)  val += xp[v];
        if (RELU) val = fmaxf(val, 0.f);
        xp[v] = val;
    }
}

// ---------------- W pre-split into B-fragment-major bf16 hi/lo ----------------
template<int K, int D>
__global__ void wsplit_k(const float* __restrict__ W, short* __restrict__ hi,
                         short* __restrict__ lo) {
    int idx = blockIdx.x * blockDim.x + threadIdx.x;
    if (idx >= K * D) return;
    int j = idx & 7;
    int l = (idx >> 3) & 63;
    int rest = idx >> 9;
    int kb = rest % (K / 32);
    int t = rest / (K / 32);
    int k = kb * 32 + (l >> 4) * 8 + j;
    int ncol = t * 16 + (l & 15);
    bf16split(W[(size_t)k * D + ncol], hi[idx], lo[idx]);
}

// ---------------- MFMA GEMM: Hout[N,D] = A[N,K] @ W[K,D] (+bias)(+relu) ----------------
template<int K, int D, bool BIAS, bool RELU, bool OUTBF>
__global__ __launch_bounds__(256) void gemm_mfma(
        const float* __restrict__ A, const short* __restrict__ Whi,
        const short* __restrict__ Wlo, const float* __restrict__ b,
        void* __restrict__ Hout, int n) {
    constexpr int LDK = K + 8;
    constexpr int NT = D / 64;
    constexpr int KB = K / 32;
    __shared__ short Ahi[64 * LDK];
    __shared__ short Alo[64 * LDK];

    int row0 = blockIdx.x * 64;
    constexpr int NF4 = 64 * (K / 4);
    for (int idx = threadIdx.x; idx < NF4; idx += 256) {
        int r = idx / (K / 4), c4 = idx % (K / 4);
        float4 v;
        if (row0 + r < n) v = ((const float4*)A)[(size_t)(row0 + r) * (K / 4) + c4];
        else v = make_float4(0.f, 0.f, 0.f, 0.f);
        int base = r * LDK + c4 * 4;
        bf16split(v.x, Ahi[base + 0], Alo[base + 0]);
        bf16split(v.y, Ahi[base + 1], Alo[base + 1]);
        bf16split(v.z, Ahi[base + 2], Alo[base + 2]);
        bf16split(v.w, Ahi[base + 3], Alo[base + 3]);
    }
    __syncthreads();

    int wave = threadIdx.x >> 6, lane = threadIdx.x & 63;
    int quad = lane >> 4, lane15 = lane & 15;

    floatx4 acc[4][NT];
#pragma unroll
    for (int mt = 0; mt < 4; ++mt)
#pragma unroll
        for (int nt = 0; nt < NT; ++nt)
            acc[mt][nt] = (floatx4){0.f, 0.f, 0.f, 0.f};

#pragma unroll
    for (int kb = 0; kb < KB; ++kb) {
        short8 ah[4], al[4];
#pragma unroll
        for (int mt = 0; mt < 4; ++mt) {
            int addr = (mt * 16 + lane15) * LDK + kb * 32 + quad * 8;
            ah[mt] = *(const short8*)&Ahi[addr];
            al[mt] = *(const short8*)&Alo[addr];
        }
        short8 bh[NT], bl[NT];
#pragma unroll
        for (int nt = 0; nt < NT; ++nt) {
            int t = wave * NT + nt;
            size_t fb = ((size_t)(t * KB + kb) * 64 + lane) * 8;
            bh[nt] = *(const short8*)&Whi[fb];
            bl[nt] = *(const short8*)&Wlo[fb];
        }
#pragma unroll
        for (int mt = 0; mt < 4; ++mt)
#pragma unroll
            for (int nt = 0; nt < NT; ++nt) {
                acc[mt][nt] = __builtin_amdgcn_mfma_f32_16x16x32_bf16(ah[mt], bh[nt], acc[mt][nt], 0, 0, 0);
                acc[mt][nt] = __builtin_amdgcn_mfma_f32_16x16x32_bf16(ah[mt], bl[nt], acc[mt][nt], 0, 0, 0);
                acc[mt][nt] = __builtin_amdgcn_mfma_f32_16x16x32_bf16(al[mt], bh[nt], acc[mt][nt], 0, 0, 0);
            }
    }

#pragma unroll
    for (int mt = 0; mt < 4; ++mt) {
#pragma unroll
        for (int nt = 0; nt < NT; ++nt) {
            int col = wave * (NT * 16) + nt * 16 + lane15;
            float bj = BIAS ? b[col] : 0.f;
#pragma unroll
            for (int reg = 0; reg < 4; ++reg) {
                int row = row0 + mt * 16 + quad * 4 + reg;
                if (row < n) {
                    float v = acc[mt][nt][reg] + bj;
                    if (RELU) v = fmaxf(v, 0.f);
                    if (OUTBF) ((unsigned short*)Hout)[(size_t)row * D + col] = f2b(v);
                    else       ((float*)Hout)[(size_t)row * D + col] = v;
                }
            }
        }
    }
}

// ---------------- graph readout ----------------
__global__ void gsum_kernel(const int* __restrict__ batch, const float* __restrict__ X,
                            float* __restrict__ gsum) {
    int i = blockIdx.x;
    int j = threadIdx.x;
    atomicAdd(&gsum[batch[i] * OUT_D + j], X[(size_t)i * OUT_D + j]);
}

__global__ void final_kernel(const float* __restrict__ gsum, const int* __restrict__ cnt,
                             float* __restrict__ out) {
    int g = blockIdx.x;
    int j = threadIdx.x;
    int c = cnt[g];
    float cf = (float)(c > 0 ? c : 1);
    out[g * OUT_D + j] = gsum[g * OUT_D + j] / cf;
}

extern "C" void kernel_launch(void* const* d_in, const int* in_sizes, int n_in,
                              void* d_out, int out_size, void* d_ws, size_t ws_size,
                              hipStream_t stream) {
    const int* node_ids = (const int*)d_in[0];
    const int* edge_index = (const int*)d_in[1];
    const int* batch = (const int*)d_in[2];
    const float* embed = (const float*)d_in[3];
    const float* W_in  = (const float*)d_in[4];
    const float* b_in  = (const float*)d_in[5];
    const float* W_h1  = (const float*)d_in[6];
    const float* b_h1  = (const float*)d_in[7];
    const float* W_h2  = (const float*)d_in[8];
    const float* b_h2  = (const float*)d_in[9];
    const float* W_out = (const float*)d_in[10];
    const float* b_out = (const float*)d_in[11];
    float* out = (float*)d_out;

    const int* src = edge_index;
    const int* dst = edge_index + N_EDGES;

    char* w = (char*)d_ws;
    size_t o = 0;
    auto alloc = [&](size_t bytes) -> void* {
        void* p = w + o;
        o = (o + bytes + 255) & ~(size_t)255;
        return p;
    };
    int*   deg      = (int*)alloc((size_t)N_NODES * sizeof(int));
    float* dinv     = (float*)alloc((size_t)N_NODES * sizeof(float));
    int*   cnt      = (int*)alloc((size_t)NGRAPH * sizeof(int));
    float* gsum     = (float*)alloc((size_t)NGRAPH * OUT_D * sizeof(float));
    int*   row_start= (int*)alloc((size_t)(N_NODES + 1) * sizeof(int));
    int*   cursor   = (int*)alloc((size_t)N_NODES * sizeof(int));
    int*   bsum     = (int*)alloc((size_t)SCAN_B * sizeof(int));
    int*   boff     = (int*)alloc((size_t)SCAN_B * sizeof(int));
    int*   csr_src  = (int*)alloc((size_t)N_EDGES * sizeof(int));
    float* csr_norm = (float*)alloc((size_t)N_EDGES * sizeof(float));
    float* X        = (float*)alloc((size_t)N_NODES * HID_D * sizeof(float));     // fp32 residual
    unsigned short* H16 = (unsigned short*)alloc((size_t)N_NODES * HID_D * sizeof(short)); // bf16 GEMM out
    float* A1       = (float*)alloc((size_t)N_NODES * 128 * sizeof(float));       // fp32 agg out (128-d)
    short* Whi_in   = (short*)alloc((size_t)EMB_D * HID_D * sizeof(short));
    short* Wlo_in   = (short*)alloc((size_t)EMB_D * HID_D * sizeof(short));
    short* Whi_h1   = (short*)alloc((size_t)HID_D * HID_D * sizeof(short));
    short* Wlo_h1   = (short*)alloc((size_t)HID_D * HID_D * sizeof(short));
    short* Whi_h2   = (short*)alloc((size_t)HID_D * HID_D * sizeof(short));
    short* Wlo_h2   = (short*)alloc((size_t)HID_D * HID_D * sizeof(short));
    short* Whi_out  = (short*)alloc((size_t)HID_D * OUT_D * sizeof(short));
    short* Wlo_out  = (short*)alloc((size_t)HID_D * OUT_D * sizeof(short));
    unsigned short* E16 = H16;               // layer-1 bf16 embeddings alias
    unsigned short* H4  = H16;               // layer-4 bf16 GEMM out [N,128] alias
    (void)ws_size;

    hipMemsetAsync(deg, 0, (size_t)N_NODES * sizeof(int), stream);
    hipMemsetAsync(cnt, 0, (size_t)NGRAPH * sizeof(int), stream);
    hipMemsetAsync(gsum, 0, (size_t)NGRAPH * OUT_D * sizeof(float), stream);

    deg_cnt_kernel<<<(N_EDGES + 255) / 256, 256, 0, stream>>>(dst, batch, deg, cnt);
    scan_a<<<SCAN_B, 256, 0, stream>>>(deg, bsum, dinv);
    scan_b<<<1, 256, 0, stream>>>(bsum, boff);
    scan_c<<<SCAN_B, 256, 0, stream>>>(deg, boff, row_start, cursor);
    scatter_kernel<<<(N_EDGES + 255) / 256, 256, 0, stream>>>(src, dst, dinv, cursor,
                                                              csr_src, csr_norm);

    wsplit_k<EMB_D, HID_D><<<(EMB_D * HID_D + 255) / 256, 256, 0, stream>>>(W_in, Whi_in, Wlo_in);
    wsplit_k<HID_D, HID_D><<<(HID_D * HID_D + 255) / 256, 256, 0, stream>>>(W_h1, Whi_h1, Wlo_h1);
    wsplit_k<HID_D, HID_D><<<(HID_D * HID_D + 255) / 256, 256, 0, stream>>>(W_h2, Whi_h2, Wlo_h2);
    wsplit_k<HID_D, OUT_D><<<(HID_D * OUT_D + 255) / 256, 256, 0, stream>>>(W_out, Whi_out, Wlo_out);

    const int gemm_grid = (N_NODES + 63) / 64;
    const int agg_grid = (N_NODES + 3) / 4;

    // ---- Layer 1: gather emb (bf16, 128), agg at 128, MFMA GEMM 128->256 +bias+relu ----
    gather_bf16<<<(N_NODES * (EMB_D / 4) + 255) / 256, 256, 0, stream>>>(node_ids, embed, E16);
    agg_node<128, false, false, false><<<agg_grid, 256, 0, stream>>>(
        row_start, csr_src, csr_norm, dinv, E16, nullptr, A1);
    gemm_mfma<128, 256, true, true, false><<<gemm_grid, 256, 0, stream>>>(A1, Whi_in, Wlo_in, b_in, X, N_NODES);

    // ---- Layer 2: MFMA GEMM 256->256 (bf16 out), fused agg+self+bias+residual+relu ----
    gemm_mfma<256, 256, false, false, true><<<gemm_grid, 256, 0, stream>>>(X, Whi_h1, Wlo_h1, nullptr, H16, N_NODES);
    agg_node<256, true, true, true><<<agg_grid, 256, 0, stream>>>(
        row_start, csr_src, csr_norm, dinv, H16, b_h1, X);

    // ---- Layer 3: same ----
    gemm_mfma<256, 256, false, false, true><<<gemm_grid, 256, 0, stream>>>(X, Whi_h2, Wlo_h2, nullptr, H16, N_NODES);
    agg_node<256, true, true, true><<<agg_grid, 256, 0, stream>>>(
        row_start, csr_src, csr_norm, dinv, H16, b_h2, X);

    // ---- Layer 4: MFMA GEMM 256->128 (bf16 out), agg at 128 +bias ----
    gemm_mfma<256, 128, false, false, true><<<gemm_grid, 256, 0, stream>>>(X, Whi_out, Wlo_out, nullptr, H4, N_NODES);
    agg_node<128, true, false, false><<<agg_grid, 256, 0, stream>>>(
        row_start, csr_src, csr_norm, dinv, H4, b_out, A1);

    // ---- readout ----
    gsum_kernel<<<N_NODES, OUT_D, 0, stream>>>(batch, A1, gsum);
    final_kernel<<<NGRAPH, OUT_D, 0, stream>>>(gsum, cnt, out);
}

// Round 7
// 554.364 us; speedup vs baseline: 5.4314x; 1.1277x over previous
//
#include <hip/hip_runtime.h>
#include <hip/hip_bf16.h>

#define N_NODES 50000
#define N_EDGES 800000
#define EMB_D 128
#define HID_D 256
#define OUT_D 128
#define NGRAPH 256

#define SCAN_B ((N_NODES + 256) / 256)   // 196 blocks covers N_NODES+1 slots

typedef __attribute__((ext_vector_type(8))) short short8;
typedef __attribute__((ext_vector_type(4))) float floatx4;
typedef __attribute__((ext_vector_type(2))) unsigned short ushortx2;
typedef __attribute__((ext_vector_type(4))) unsigned short ushortx4;

__device__ inline void bf16split(float x, short& hi, short& lo) {
    __hip_bfloat16 h = __float2bfloat16(x);
    float r = x - __bfloat162float(h);
    __hip_bfloat16 l = __float2bfloat16(r);
    hi = *reinterpret_cast<short*>(&h);
    lo = *reinterpret_cast<short*>(&l);
}

__device__ inline unsigned short f2b(float f) {
    __hip_bfloat16 h = __float2bfloat16(f);
    return *reinterpret_cast<unsigned short*>(&h);
}

__device__ inline float b2f(unsigned short u) {
    union { unsigned int i; float f; } c;
    c.i = ((unsigned int)u) << 16;
    return c.f;
}

template<int VPL> struct UVec;
template<> struct UVec<2> { using T = ushortx2; };
template<> struct UVec<4> { using T = ushortx4; };

// ---------------- rank pass: 4-shard degree histogram + per-edge rank ----------------
__global__ void rank_kernel(const int* __restrict__ dst, int* __restrict__ deg4,
                            int* __restrict__ pos) {
    int e = blockIdx.x * blockDim.x + threadIdx.x;
    if (e >= N_EDGES) return;
    pos[e] = atomicAdd(&deg4[(size_t)(e & 3) * N_NODES + dst[e]], 1);
}

// ---------------- graph boundaries via binary search (batch is sorted) ----------------
__global__ void bstart_kernel(const int* __restrict__ batch, int* __restrict__ bstart) {
    int g = threadIdx.x;  // 0..256
    if (g > NGRAPH) return;
    // lower_bound: first i with batch[i] >= g
    int lo = 0, hi = N_NODES;
    while (lo < hi) {
        int mid = (lo + hi) >> 1;
        if (batch[mid] < g) lo = mid + 1;
        else hi = mid;
    }
    bstart[g] = lo;
}

// ---------------- scan phase A: merge shards, block sums, dinv, shard bases ----------------
__global__ void scan_a(const int* __restrict__ deg4, int* __restrict__ degt,
                       int* __restrict__ sb4, int* __restrict__ bsum,
                       float* __restrict__ dinv) {
    __shared__ int red[256];
    int t = threadIdx.x;
    int i = blockIdx.x * 256 + t;
    int tot = 0;
    if (i < N_NODES) {
        int d0 = deg4[i];
        int d1 = deg4[(size_t)N_NODES + i];
        int d2 = deg4[(size_t)2 * N_NODES + i];
        int d3 = deg4[(size_t)3 * N_NODES + i];
        tot = d0 + d1 + d2 + d3;
        degt[i] = tot;
        dinv[i] = rsqrtf((float)tot + 1.0f);
        sb4[i] = 0;
        sb4[(size_t)N_NODES + i] = d0;
        sb4[(size_t)2 * N_NODES + i] = d0 + d1;
        sb4[(size_t)3 * N_NODES + i] = d0 + d1 + d2;
    }
    red[t] = tot;
    __syncthreads();
    for (int off = 128; off > 0; off >>= 1) {
        if (t < off) red[t] += red[t + off];
        __syncthreads();
    }
    if (t == 0) bsum[blockIdx.x] = red[0];
}

// ---------------- phase B: exclusive scan of block sums (1 block) ----------------
__global__ void scan_b(const int* __restrict__ bsum, int* __restrict__ boff) {
    __shared__ int s[256];
    int t = threadIdx.x;
    s[t] = (t < SCAN_B) ? bsum[t] : 0;
    __syncthreads();
    for (int off = 1; off < 256; off <<= 1) {
        int v = (t >= off) ? s[t - off] : 0;
        __syncthreads();
        s[t] += v;
        __syncthreads();
    }
    if (t < SCAN_B) boff[t] = (t == 0) ? 0 : s[t - 1];
}

// ---------------- phase C: in-block scan + offset -> row_start ----------------
__global__ void scan_c(const int* __restrict__ degt, const int* __restrict__ boff,
                       int* __restrict__ row_start) {
    __shared__ int s[256];
    int t = threadIdx.x;
    int i = blockIdx.x * 256 + t;
    int v = (i < N_NODES) ? degt[i] : 0;
    s[t] = v;
    __syncthreads();
    for (int off = 1; off < 256; off <<= 1) {
        int x = (t >= off) ? s[t - off] : 0;
        __syncthreads();
        s[t] += x;
        __syncthreads();
    }
    int excl = s[t] - v;
    int rs = boff[blockIdx.x] + excl;
    if (i <= N_NODES) row_start[i] = rs;
}

// ---------------- atomic-free CSR scatter ----------------
__global__ void scatter_kernel(const int* __restrict__ src, const int* __restrict__ dst,
                               const int* __restrict__ pos, const int* __restrict__ row_start,
                               const int* __restrict__ sb4, const float* __restrict__ dinv,
                               int* __restrict__ csr_src, float* __restrict__ csr_norm) {
    int e = blockIdx.x * blockDim.x + threadIdx.x;
    if (e >= N_EDGES) return;
    int s = src[e], d = dst[e];
    int slot = row_start[d] + sb4[(size_t)(e & 3) * N_NODES + d] + pos[e];
    csr_src[slot] = s;
    csr_norm[slot] = dinv[s] * dinv[d];
}

// ---------------- embedding gather -> bf16 rows ----------------
__global__ void gather_bf16(const int* __restrict__ ids, const float* __restrict__ embed,
                            unsigned short* __restrict__ X0) {
    int idx = blockIdx.x * blockDim.x + threadIdx.x;  // one float4 each
    const int V = EMB_D / 4;
    if (idx >= N_NODES * V) return;
    int row = idx / V, c = idx % V;
    float4 v = ((const float4*)embed)[(size_t)ids[row] * V + c];
    ushortx4 u;
    u[0] = f2b(v.x); u[1] = f2b(v.y); u[2] = f2b(v.z); u[3] = f2b(v.w);
    ((ushortx4*)X0)[idx] = u;
}

// ---------------- fused aggregation (bf16 gather, fp32 out): one wave per node ----
template<int D, bool HASB, bool RES, bool RELU>
__global__ __launch_bounds__(256) void agg_node(
        const int* __restrict__ row_start, const int* __restrict__ csr_src,
        const float* __restrict__ csr_norm, const float* __restrict__ dinv,
        const unsigned short* __restrict__ H, const float* __restrict__ b,
        float* __restrict__ OUT) {
    constexpr int VPL = D / 64;
    using UV = typename UVec<VPL>::T;
    int wave = threadIdx.x >> 6, lane = threadIdx.x & 63;
    int i = blockIdx.x * 4 + wave;
    if (i >= N_NODES) return;
    const int off = lane * VPL;
    float acc0[VPL], acc1[VPL];
#pragma unroll
    for (int v = 0; v < VPL; ++v) { acc0[v] = 0.f; acc1[v] = 0.f; }
    int e0 = row_start[i], e1 = row_start[i + 1];
    int e = e0;
    for (; e + 3 < e1; e += 4) {
        int s0 = csr_src[e], s1 = csr_src[e + 1], s2 = csr_src[e + 2], s3 = csr_src[e + 3];
        float n0 = csr_norm[e], n1 = csr_norm[e + 1], n2 = csr_norm[e + 2], n3 = csr_norm[e + 3];
        UV u0 = *(const UV*)(H + (size_t)s0 * D + off);
        UV u1 = *(const UV*)(H + (size_t)s1 * D + off);
        UV u2 = *(const UV*)(H + (size_t)s2 * D + off);
        UV u3 = *(const UV*)(H + (size_t)s3 * D + off);
#pragma unroll
        for (int v = 0; v < VPL; ++v) acc0[v] = fmaf(b2f(u0[v]), n0, acc0[v]);
#pragma unroll
        for (int v = 0; v < VPL; ++v) acc1[v] = fmaf(b2f(u1[v]), n1, acc1[v]);
#pragma unroll
        for (int v = 0; v < VPL; ++v) acc0[v] = fmaf(b2f(u2[v]), n2, acc0[v]);
#pragma unroll
        for (int v = 0; v < VPL; ++v) acc1[v] = fmaf(b2f(u3[v]), n3, acc1[v]);
    }
    for (; e < e1; ++e) {
        int s0 = csr_src[e];
        float n0 = csr_norm[e];
        UV u0 = *(const UV*)(H + (size_t)s0 * D + off);
#pragma unroll
        for (int v = 0; v < VPL; ++v) acc0[v] = fmaf(b2f(u0[v]), n0, acc0[v]);
    }
    float di = dinv[i];
    float d2 = di * di;
    UV us = *(const UV*)(H + (size_t)i * D + off);
    float* xp = OUT + (size_t)i * D + off;
#pragma unroll
    for (int v = 0; v < VPL; ++v) {
        float val = acc0[v] + acc1[v];
        val = fmaf(b2f(us[v]), d2, val);
        if (HASB) val += b[off + v];
        if (RES)  val += xp[v];
        if (RELU) val = fmaxf(val, 0.f);
        xp[v] = val;
    }
}

// ---------------- W pre-split into B-fragment-major bf16 hi/lo ----------------
template<int K, int D>
__global__ void wsplit_k(const float* __restrict__ W, short* __restrict__ hi,
                         short* __restrict__ lo) {
    int idx = blockIdx.x * blockDim.x + threadIdx.x;
    if (idx >= K * D) return;
    int j = idx & 7;
    int l = (idx >> 3) & 63;
    int rest = idx >> 9;
    int kb = rest % (K / 32);
    int t = rest / (K / 32);
    int k = kb * 32 + (l >> 4) * 8 + j;
    int ncol = t * 16 + (l & 15);
    bf16split(W[(size_t)k * D + ncol], hi[idx], lo[idx]);
}

// ---------------- MFMA GEMM: Hout[N,D] = A[N,K] @ W[K,D] (+bias)(+relu) ----------------
template<int K, int D, bool BIAS, bool RELU, bool OUTBF>
__global__ __launch_bounds__(256) void gemm_mfma(
        const float* __restrict__ A, const short* __restrict__ Whi,
        const short* __restrict__ Wlo, const float* __restrict__ b,
        void* __restrict__ Hout, int n) {
    constexpr int LDK = K + 8;
    constexpr int NT = D / 64;
    constexpr int KB = K / 32;
    __shared__ short Ahi[64 * LDK];
    __shared__ short Alo[64 * LDK];

    int row0 = blockIdx.x * 64;
    constexpr int NF4 = 64 * (K / 4);
    for (int idx = threadIdx.x; idx < NF4; idx += 256) {
        int r = idx / (K / 4), c4 = idx % (K / 4);
        float4 v;
        if (row0 + r < n) v = ((const float4*)A)[(size_t)(row0 + r) * (K / 4) + c4];
        else v = make_float4(0.f, 0.f, 0.f, 0.f);
        int base = r * LDK + c4 * 4;
        bf16split(v.x, Ahi[base + 0], Alo[base + 0]);
        bf16split(v.y, Ahi[base + 1], Alo[base + 1]);
        bf16split(v.z, Ahi[base + 2], Alo[base + 2]);
        bf16split(v.w, Ahi[base + 3], Alo[base + 3]);
    }
    __syncthreads();

    int wave = threadIdx.x >> 6, lane = threadIdx.x & 63;
    int quad = lane >> 4, lane15 = lane & 15;

    floatx4 acc[4][NT];
#pragma unroll
    for (int mt = 0; mt < 4; ++mt)
#pragma unroll
        for (int nt = 0; nt < NT; ++nt)
            acc[mt][nt] = (floatx4){0.f, 0.f, 0.f, 0.f};

#pragma unroll
    for (int kb = 0; kb < KB; ++kb) {
        short8 ah[4], al[4];
#pragma unroll
        for (int mt = 0; mt < 4; ++mt) {
            int addr = (mt * 16 + lane15) * LDK + kb * 32 + quad * 8;
            ah[mt] = *(const short8*)&Ahi[addr];
            al[mt] = *(const short8*)&Alo[addr];
        }
        short8 bh[NT], bl[NT];
#pragma unroll
        for (int nt = 0; nt < NT; ++nt) {
            int t = wave * NT + nt;
            size_t fb = ((size_t)(t * KB + kb) * 64 + lane) * 8;
            bh[nt] = *(const short8*)&Whi[fb];
            bl[nt] = *(const short8*)&Wlo[fb];
        }
#pragma unroll
        for (int mt = 0; mt < 4; ++mt)
#pragma unroll
            for (int nt = 0; nt < NT; ++nt) {
                acc[mt][nt] = __builtin_amdgcn_mfma_f32_16x16x32_bf16(ah[mt], bh[nt], acc[mt][nt], 0, 0, 0);
                acc[mt][nt] = __builtin_amdgcn_mfma_f32_16x16x32_bf16(ah[mt], bl[nt], acc[mt][nt], 0, 0, 0);
                acc[mt][nt] = __builtin_amdgcn_mfma_f32_16x16x32_bf16(al[mt], bh[nt], acc[mt][nt], 0, 0, 0);
            }
    }

#pragma unroll
    for (int mt = 0; mt < 4; ++mt) {
#pragma unroll
        for (int nt = 0; nt < NT; ++nt) {
            int col = wave * (NT * 16) + nt * 16 + lane15;
            float bj = BIAS ? b[col] : 0.f;
#pragma unroll
            for (int reg = 0; reg < 4; ++reg) {
                int row = row0 + mt * 16 + quad * 4 + reg;
                if (row < n) {
                    float v = acc[mt][nt][reg] + bj;
                    if (RELU) v = fmaxf(v, 0.f);
                    if (OUTBF) ((unsigned short*)Hout)[(size_t)row * D + col] = f2b(v);
                    else       ((float*)Hout)[(size_t)row * D + col] = v;
                }
            }
        }
    }
}

// ---------------- readout: one block per graph, atomic-free mean ----------------
__global__ void graph_mean(const int* __restrict__ bstart, const float* __restrict__ X,
                           float* __restrict__ out) {
    int g = blockIdx.x;
    int r0 = bstart[g], r1 = bstart[g + 1];
    int col = threadIdx.x & 127, rr = threadIdx.x >> 7;  // 2 rows in flight
    float acc = 0.f;
    for (int r = r0 + rr; r < r1; r += 2)
        acc += X[(size_t)r * OUT_D + col];
    __shared__ float sh[128];
    if (rr == 1) sh[col] = acc;
    __syncthreads();
    if (rr == 0) {
        float tot = acc + sh[col];
        int c = r1 - r0;
        out[(size_t)g * OUT_D + col] = tot / (float)(c > 0 ? c : 1);
    }
}

extern "C" void kernel_launch(void* const* d_in, const int* in_sizes, int n_in,
                              void* d_out, int out_size, void* d_ws, size_t ws_size,
                              hipStream_t stream) {
    const int* node_ids = (const int*)d_in[0];
    const int* edge_index = (const int*)d_in[1];
    const int* batch = (const int*)d_in[2];
    const float* embed = (const float*)d_in[3];
    const float* W_in  = (const float*)d_in[4];
    const float* b_in  = (const float*)d_in[5];
    const float* W_h1  = (const float*)d_in[6];
    const float* b_h1  = (const float*)d_in[7];
    const float* W_h2  = (const float*)d_in[8];
    const float* b_h2  = (const float*)d_in[9];
    const float* W_out = (const float*)d_in[10];
    const float* b_out = (const float*)d_in[11];
    float* out = (float*)d_out;

    const int* src = edge_index;
    const int* dst = edge_index + N_EDGES;

    char* w = (char*)d_ws;
    size_t o = 0;
    auto alloc = [&](size_t bytes) -> void* {
        void* p = w + o;
        o = (o + bytes + 255) & ~(size_t)255;
        return p;
    };
    int*   deg4     = (int*)alloc((size_t)4 * N_NODES * sizeof(int));
    int*   sb4      = (int*)alloc((size_t)4 * N_NODES * sizeof(int));
    int*   degt     = (int*)alloc((size_t)N_NODES * sizeof(int));
    int*   pos      = (int*)alloc((size_t)N_EDGES * sizeof(int));
    float* dinv     = (float*)alloc((size_t)N_NODES * sizeof(float));
    int*   bstart   = (int*)alloc((size_t)(NGRAPH + 1) * sizeof(int));
    int*   row_start= (int*)alloc((size_t)(N_NODES + 1) * sizeof(int));
    int*   bsum     = (int*)alloc((size_t)SCAN_B * sizeof(int));
    int*   boff     = (int*)alloc((size_t)SCAN_B * sizeof(int));
    int*   csr_src  = (int*)alloc((size_t)N_EDGES * sizeof(int));
    float* csr_norm = (float*)alloc((size_t)N_EDGES * sizeof(float));
    float* X        = (float*)alloc((size_t)N_NODES * HID_D * sizeof(float));     // fp32 residual
    unsigned short* H16 = (unsigned short*)alloc((size_t)N_NODES * HID_D * sizeof(short)); // bf16 GEMM out
    float* A1       = (float*)alloc((size_t)N_NODES * 128 * sizeof(float));       // fp32 agg out (128-d)
    short* Whi_in   = (short*)alloc((size_t)EMB_D * HID_D * sizeof(short));
    short* Wlo_in   = (short*)alloc((size_t)EMB_D * HID_D * sizeof(short));
    short* Whi_h1   = (short*)alloc((size_t)HID_D * HID_D * sizeof(short));
    short* Wlo_h1   = (short*)alloc((size_t)HID_D * HID_D * sizeof(short));
    short* Whi_h2   = (short*)alloc((size_t)HID_D * HID_D * sizeof(short));
    short* Wlo_h2   = (short*)alloc((size_t)HID_D * HID_D * sizeof(short));
    short* Whi_out  = (short*)alloc((size_t)HID_D * OUT_D * sizeof(short));
    short* Wlo_out  = (short*)alloc((size_t)HID_D * OUT_D * sizeof(short));
    unsigned short* E16 = H16;               // layer-1 bf16 embeddings alias
    unsigned short* H4  = H16;               // layer-4 bf16 GEMM out [N,128] alias
    (void)ws_size;

    hipMemsetAsync(deg4, 0, (size_t)4 * N_NODES * sizeof(int), stream);

    rank_kernel<<<(N_EDGES + 255) / 256, 256, 0, stream>>>(dst, deg4, pos);
    bstart_kernel<<<1, 512, 0, stream>>>(batch, bstart);
    scan_a<<<SCAN_B, 256, 0, stream>>>(deg4, degt, sb4, bsum, dinv);
    scan_b<<<1, 256, 0, stream>>>(bsum, boff);
    scan_c<<<SCAN_B, 256, 0, stream>>>(degt, boff, row_start);
    scatter_kernel<<<(N_EDGES + 255) / 256, 256, 0, stream>>>(src, dst, pos, row_start,
                                                              sb4, dinv, csr_src, csr_norm);

    wsplit_k<EMB_D, HID_D><<<(EMB_D * HID_D + 255) / 256, 256, 0, stream>>>(W_in, Whi_in, Wlo_in);
    wsplit_k<HID_D, HID_D><<<(HID_D * HID_D + 255) / 256, 256, 0, stream>>>(W_h1, Whi_h1, Wlo_h1);
    wsplit_k<HID_D, HID_D><<<(HID_D * HID_D + 255) / 256, 256, 0, stream>>>(W_h2, Whi_h2, Wlo_h2);
    wsplit_k<HID_D, OUT_D><<<(HID_D * OUT_D + 255) / 256, 256, 0, stream>>>(W_out, Whi_out, Wlo_out);

    const int gemm_grid = (N_NODES + 63) / 64;
    const int agg_grid = (N_NODES + 3) / 4;

    // ---- Layer 1: gather emb (bf16, 128), agg at 128, MFMA GEMM 128->256 +bias+relu ----
    gather_bf16<<<(N_NODES * (EMB_D / 4) + 255) / 256, 256, 0, stream>>>(node_ids, embed, E16);
    agg_node<128, false, false, false><<<agg_grid, 256, 0, stream>>>(
        row_start, csr_src, csr_norm, dinv, E16, nullptr, A1);
    gemm_mfma<128, 256, true, true, false><<<gemm_grid, 256, 0, stream>>>(A1, Whi_in, Wlo_in, b_in, X, N_NODES);

    // ---- Layer 2: MFMA GEMM 256->256 (bf16 out), fused agg+self+bias+residual+relu ----
    gemm_mfma<256, 256, false, false, true><<<gemm_grid, 256, 0, stream>>>(X, Whi_h1, Wlo_h1, nullptr, H16, N_NODES);
    agg_node<256, true, true, true><<<agg_grid, 256, 0, stream>>>(
        row_start, csr_src, csr_norm, dinv, H16, b_h1, X);

    // ---- Layer 3: same ----
    gemm_mfma<256, 256, false, false, true><<<gemm_grid, 256, 0, stream>>>(X, Whi_h2, Wlo_h2, nullptr, H16, N_NODES);
    agg_node<256, true, true, true><<<agg_grid, 256, 0, stream>>>(
        row_start, csr_src, csr_norm, dinv, H16, b_h2, X);

    // ---- Layer 4: MFMA GEMM 256->128 (bf16 out), agg at 128 +bias ----
    gemm_mfma<256, 128, false, false, true><<<gemm_grid, 256, 0, stream>>>(X, Whi_out, Wlo_out, nullptr, H4, N_NODES);
    agg_node<128, true, false, false><<<agg_grid, 256, 0, stream>>>(
        row_start, csr_src, csr_norm, dinv, H4, b_out, A1);

    // ---- readout: atomic-free per-graph mean (batch sorted) ----
    graph_mean<<<NGRAPH, 256, 0, stream>>>(bstart, A1, out);
}